// Round 12
// baseline (386.115 us; speedup 1.0000x reference)
//
#include <hip/hip_runtime.h>
#include <math.h>

#define NU 50000
#define NI 50000
#define NN 50000
#define DD 64
#define HHID 128
#define EE 500000
#define NEG_SLOPE 0.01f
#define NBKT 196           // coarse buckets of 256 nodes (key>>8)
#define CAP 3072           // capacity per (image,bucket) coarse region (mean 2551, +10 sigma)
#define TILE 8192          // tiles; tile_n always %4 == 0
#define TPG 62             // tiles per graph = ceil(500000/8192)
#define P1T 512            // part1 threads per block
#define NIMG 12            // 8 dst-keyed CSR images + 4 src-keyed count-only images
#define AGGB 1563          // agg blocks per graph = ceil(50000/32)
#define SEMB 512           // sem_att blocks per instance

typedef _Float16 half_t;
typedef _Float16 half8 __attribute__((ext_vector_type(8)));
typedef _Float16 half4 __attribute__((ext_vector_type(4)));
typedef float f32x4 __attribute__((ext_vector_type(4)));
union H4 { uint2 u; half_t h[4]; };
union H8 { uint4 u; half_t h[8]; };
union HS { half8 h; int i[4]; uint4 u; };
union HS4 { half4 h; int i[2]; uint2 u; };
union HC { unsigned short us; half_t h; };

struct Ptr4c { const float* p[4]; };
struct Ptr4m { float*       p[4]; };
struct EdgeArgs { const int* src[8]; const int* dst[8]; };
struct GatArgs { const half_t* fsrc[4]; half_t* zout[4]; };
struct GcArgs  { const half_t* feat[4]; half_t* hout[4]; };
struct WArgs   { const float* el[4]; const float* er[4]; const int* deg_src; };
struct SemArgs { const half_t* z[4]; const float* W1[4]; const float* b1[4]; const float* w2[4]; };
struct PrepArgs {
    const float* featI; const float* featU;
    Ptr4c vi; Ptr4c vu; Ptr4m oi; Ptr4m ou;
    half_t* FBI; half_t* FBU;
    const float* W_gc; half_t* W16;
};

// ---------------- merged prep: blocks 0..3124 item dot4+cvt, 3125..6249 user, 6250 = W fragments
__global__ __launch_bounds__(256) void prep_kernel(PrepArgs pa) {
    int b = blockIdx.x;
    int t = threadIdx.x;
    if (b == 6250) {
        int g = t >> 6;
        int lane = t & 63;
        int cl = lane & 15, quad = lane >> 4;
#pragma unroll
        for (int nt = 0; nt < 4; nt++) {
#pragma unroll
            for (int kh = 0; kh < 2; kh++) {
                H8 o;
#pragma unroll
                for (int j = 0; j < 8; j++) {
                    int k = kh * 32 + quad * 8 + j;
                    int n = nt * 16 + cl;
                    o.h[j] = (half_t)pa.W_gc[g * 4096 + k * 64 + n];
                }
                *(uint4*)(pa.W16 + ((g * 8 + nt * 2 + kh) * 64 + lane) * 8) = o.u;
            }
        }
        return;
    }
    const float* feat; Ptr4c vecs; Ptr4m outs; half_t* fb16; int bb;
    if (b < 3125) { feat = pa.featI; vecs = pa.vi; outs = pa.oi; fb16 = pa.FBI; bb = b; }
    else          { feat = pa.featU; vecs = pa.vu; outs = pa.ou; fb16 = pa.FBU; bb = b - 3125; }
    int w = bb * 4 + (t >> 6);
    int lane = t & 63;
    int sub = lane >> 4, r = lane & 15;
    int node = w * 4 + sub;           // <= 49999 by construction
    float4 f = *(const float4*)(feat + node * DD + r * 4);
    H4 o16;
    o16.h[0] = (half_t)f.x; o16.h[1] = (half_t)f.y; o16.h[2] = (half_t)f.z; o16.h[3] = (half_t)f.w;
    *(uint2*)(fb16 + node * DD + r * 4) = o16.u;
#pragma unroll
    for (int j = 0; j < 4; j++) {
        float4 vv = *(const float4*)(vecs.p[j] + r * 4);
        float val = f.x * vv.x + f.y * vv.y + f.z * vv.z + f.w * vv.w;
        val += __shfl_down(val, 8);
        val += __shfl_down(val, 4);
        val += __shfl_down(val, 2);
        val += __shfl_down(val, 1);
        if (r == 0) outs.p[j][node] = val;
    }
}

// ---------------- pass 1 (v4): two-phase LDS counting-sort over 12 keyed images.
// NO global atomics anywhere.
__global__ __launch_bounds__(P1T) void part1_kernel(EdgeArgs a, int* __restrict__ ccnt,
                                                    int* __restrict__ coarse) {
    __shared__ int bc_cnt[256], bc_scan[256], bc_start[256], bc_cur[256], bc_gbase[256];
    __shared__ int stage[TILE];
    int t = threadIdx.x;
    int g = blockIdx.x / TPG;
    int tile = blockIdx.x % TPG;
    int e0 = tile * TILE;
    int tile_n = min(TILE, EE - e0);      // always % 4 == 0
    bool cnt_only = g >= 8;
    const int* gk = (cnt_only ? a.src[g - 4] : a.dst[g]) + e0;
    const int* gs = cnt_only ? gk : (a.src[g] + e0);
    if (t < 256) bc_cnt[t] = 0;
    __syncthreads();
    // phase A: key histogram (streaming int4)
    for (int pos = t * 4; pos < tile_n; pos += P1T * 4) {
        int4 k4 = *(const int4*)(gk + pos);
        atomicAdd(&bc_cnt[k4.x >> 8], 1);
        atomicAdd(&bc_cnt[k4.y >> 8], 1);
        atomicAdd(&bc_cnt[k4.z >> 8], 1);
        atomicAdd(&bc_cnt[k4.w >> 8], 1);
    }
    __syncthreads();
    if (t < 256) bc_scan[t] = bc_cnt[t];
    __syncthreads();
    for (int off = 1; off < 256; off <<= 1) {
        int v = (t < 256 && t >= off) ? bc_scan[t - off] : 0;
        __syncthreads();
        if (t < 256) bc_scan[t] += v;
        __syncthreads();
    }
    if (t < 256) {
        int st = bc_scan[t] - bc_cnt[t];
        bc_start[t] = st;
        bc_cur[t] = st;
        bc_gbase[t] = (t < NBKT && bc_cnt[t] > 0) ? atomicAdd(&ccnt[g * NBKT + t], bc_cnt[t]) : 0;
    }
    __syncthreads();
    // phase B: re-read keys (L2-hot), LDS scatter with packed bucket id
    for (int pos = t * 4; pos < tile_n; pos += P1T * 4) {
        int4 k4 = *(const int4*)(gk + pos);
        int4 s4;
        if (cnt_only) { s4 = make_int4(0, 0, 0, 0); }
        else          { s4 = *(const int4*)(gs + pos); }
        int b0 = k4.x >> 8, b1 = k4.y >> 8, b2 = k4.z >> 8, b3 = k4.w >> 8;
        int sl0 = atomicAdd(&bc_cur[b0], 1);
        int sl1 = atomicAdd(&bc_cur[b1], 1);
        int sl2 = atomicAdd(&bc_cur[b2], 1);
        int sl3 = atomicAdd(&bc_cur[b3], 1);
        stage[sl0] = s4.x | ((k4.x & 255) << 16) | (b0 << 24);
        stage[sl1] = s4.y | ((k4.y & 255) << 16) | (b1 << 24);
        stage[sl2] = s4.z | ((k4.z & 255) << 16) | (b2 << 24);
        stage[sl3] = s4.w | ((k4.w & 255) << 16) | (b3 << 24);
    }
    __syncthreads();
    // flush: bucket-sorted stage -> long contiguous global runs
    for (int j = t; j < tile_n; j += P1T) {
        int p = stage[j];
        int b = (unsigned)p >> 24;
        int pos = bc_gbase[b] + (j - bc_start[b]);
        if (pos < CAP) coarse[(g * NBKT + b) * CAP + pos] = p & 0x00FFFFFF;
    }
}

// ---------------- degree-count from src-keyed coarse buckets (images 8-11)
__global__ __launch_bounds__(256) void degcnt_kernel(const int* __restrict__ ccnt,
                                                     const int* __restrict__ coarse,
                                                     int* __restrict__ DEG_SRC) {
    __shared__ int cnt[256];
    int t = threadIdx.x;
    int g2 = blockIdx.x / NBKT;
    int b = blockIdx.x % NBKT;
    int img = 8 + g2;
    int n = min(ccnt[img * NBKT + b], CAP);
    cnt[t] = 0;
    __syncthreads();
    const int* pairs = coarse + (img * NBKT + b) * CAP;
    for (int i = t; i < n; i += 256) atomicAdd(&cnt[(pairs[i] >> 16) & 255], 1);
    __syncthreads();
    int v = (b << 8) + t;
    if (v < NN) DEG_SRC[g2 * NN + v] = cnt[t];
}

// ---------------- pass 2: per (graph,bucket) counting sort -> CSR with packed (w16<<16 | src)
__global__ __launch_bounds__(256) void part2_kernel(const int* __restrict__ ccnt,
                                                    const int* __restrict__ coarse,
                                                    WArgs wa,
                                                    int* __restrict__ bucket,
                                                    int2* __restrict__ RD) {
    __shared__ int sb[256];
    __shared__ int cnt5[256], off5[256], s2[256];
    __shared__ int ordered[CAP];
    int t = threadIdx.x;
    int g = blockIdx.x / NBKT;
    int b = blockIdx.x % NBKT;
    int ccv = (t < NBKT) ? min(ccnt[g * NBKT + t], CAP) : 0;
    sb[t] = ccv;
    cnt5[t] = 0;
    __syncthreads();
    for (int off = 1; off < 256; off <<= 1) {
        int vv = (t >= off) ? sb[t - off] : 0;
        __syncthreads();
        sb[t] += vv;
        __syncthreads();
    }
    int base = (b > 0) ? sb[b - 1] : 0;
    int n = sb[b] - base;
    int node0 = b << 8;
    const int* pairs = coarse + (g * NBKT + b) * CAP;
    for (int i = t; i < n; i += 256) atomicAdd(&cnt5[pairs[i] >> 16], 1);
    __syncthreads();
    int myc = cnt5[t];
    s2[t] = myc;
    __syncthreads();
    for (int off = 1; off < 256; off <<= 1) {
        int vv = (t >= off) ? s2[t - off] : 0;
        __syncthreads();
        s2[t] += vv;
        __syncthreads();
    }
    int ex = s2[t] - myc;
    off5[t] = ex;
    int v = node0 + t;
    if (v < NN) RD[g * NN + v] = make_int2(base + ex, myc);
    __syncthreads();
    int nm1 = n - 1;
    for (int ib = t; ib < n; ib += 1024) {
        int p[4];
#pragma unroll
        for (int u = 0; u < 4; u++) {
            int i = ib + u * 256;
            p[u] = pairs[(i < n) ? i : nm1];
        }
        float w[4];
        if (g < 4) {
            float a0[4], a1[4];
#pragma unroll
            for (int u = 0; u < 4; u++) a0[u] = wa.el[g][p[u] & 0xFFFF];
#pragma unroll
            for (int u = 0; u < 4; u++) a1[u] = wa.er[g][node0 + (p[u] >> 16)];
#pragma unroll
            for (int u = 0; u < 4; u++) {
                float e = a0[u] + a1[u];
                e = (e >= 0.f) ? e : NEG_SLOPE * e;
                w[u] = __expf(e);
            }
        } else {
            int dv[4];
#pragma unroll
            for (int u = 0; u < 4; u++) dv[u] = wa.deg_src[(g - 4) * NN + (p[u] & 0xFFFF)];
#pragma unroll
            for (int u = 0; u < 4; u++) w[u] = __builtin_amdgcn_rsqf((float)dv[u]);
        }
#pragma unroll
        for (int u = 0; u < 4; u++) {
            int i = ib + u * 256;
            if (i < n) {
                HC cv; cv.h = (half_t)w[u];
                int slot = atomicAdd(&off5[p[u] >> 16], 1);
                ordered[slot] = (p[u] & 0xFFFF) | ((int)cv.us << 16);
            }
        }
    }
    __syncthreads();
    int* bko = bucket + g * EE + base;
    for (int i = t; i < n; i += 256) bko[i] = ordered[i];
}

// ---------------- fused aggregation, octet-per-node, COLUMN-SPLIT 2-PASS:
// half h gathers only cols [h*32, h*32+32) -> per-pass gather working set = 50K x one
// 64B line = 3.2MB < 4MB per-XCD L2 (vs 6.4MB full rows -> 30% miss, 154MB FETCH in R11).
// h is the OUTERMOST block dim so halves are temporally separated. Same per-column edge
// order -> bit-identical output.
__global__ __launch_bounds__(256) void agg_kernel(GatArgs ga, GcArgs gc, half_t* __restrict__ AGG,
                                                  const int2* __restrict__ RD,
                                                  const int* __restrict__ bucket) {
    int h = blockIdx.x / (8 * AGGB);
    int remb = blockIdx.x % (8 * AGGB);
    int g = remb / AGGB;
    int nb = remb % AGGB;
    int t = threadIdx.x;
    int wv = t >> 6, lane = t & 63;
    int q = lane >> 3, r = lane & 7;
    int v = nb * 32 + wv * 8 + q;
    bool vok = v < NN;
    int2 rd = RD[g * NN + (vok ? v : 0)];
    int start = rd.x;
    int dg = vok ? rd.y : 0;
    const int* bk = bucket + g * EE;
    const half_t* feat = (g < 4) ? ga.fsrc[g] : gc.feat[g - 4];
    int roff = h * 32 + (r << 2);     // 4-half (8B) chunk within the 64-col row
    int obase = lane & 56;            // q*8 = base lane of this octet
    HS4 acc[4];
#pragma unroll
    for (int a = 0; a < 4; a++) { acc[a].i[0] = 0; acc[a].i[1] = 0; }
    float s_l = 0.f;
    for (int b8 = 0; b8 < dg; b8 += 8) {          // octet-uniform trip count
        int rem = dg - b8;                        // octet-uniform
        int p = bk[start + b8 + ((r < rem) ? r : 0)];
#pragma unroll
        for (int j = 0; j < 8; j++) {
            if (j < rem) {                        // octet-uniform predicate
                int pj = __shfl(p, obase + j);    // source lane in same octet -> active
                HC wj; wj.us = (unsigned short)((unsigned)pj >> 16);
                s_l += (float)wj.h;
                HS4 row; row.u = *(const uint2*)(feat + (((pj & 0xFFFF) << 6) + roff));
                half_t wh = wj.h;
                half4 ws = {wh, wh, wh, wh};
                acc[j & 3].h += row.h * ws;
            }
        }
    }
    acc[0].h += acc[1].h;
    acc[2].h += acc[3].h;
    acc[0].h += acc[2].h;
    if (g < 4) {
        float inv = (dg > 0) ? __builtin_amdgcn_rcpf(s_l) : 0.f;
        H4 o;
#pragma unroll
        for (int i = 0; i < 4; i++) {
            float x = (float)acc[0].h[i] * inv;
            x = (x > 0.f) ? x : (__expf(x) - 1.f);
            o.h[i] = (half_t)x;
        }
        if (vok) *(uint2*)(ga.zout[g] + (v << 7) + roff) = o.u;
    } else {
        float niv = (dg > 0) ? __builtin_amdgcn_rsqf((float)dg) : 1.0f;
        H4 o;
#pragma unroll
        for (int i = 0; i < 4; i++) o.h[i] = (half_t)((float)acc[0].h[i] * niv);
        if (vok) *(uint2*)(AGG + (((g - 4) * NN + v) << 6) + roff) = o.u;
    }
}

// ---------------- GC transform: wave = 16-node tile, A from AGG, B = W16 fragments, 8 MFMA
__global__ __launch_bounds__(256) void trans_kernel(GcArgs gc, const half_t* __restrict__ AGG,
                                                    const half_t* __restrict__ W16,
                                                    const float* __restrict__ b_gc) {
    int t = threadIdx.x;
    int wv = t >> 6, lane = t & 63;
    int g = blockIdx.x / 782;
    int tile = (blockIdx.x % 782) * 4 + wv;
    if (tile >= 3125) return;
    int cl = lane & 15, quad = lane >> 4;
    const half_t* ab = AGG + ((g * NN + tile * 16 + cl) << 6);
    half8 A0 = *(const half8*)(ab + quad * 8);
    half8 A1 = *(const half8*)(ab + 32 + quad * 8);
    const half_t* wbase = W16 + g * 8 * 64 * 8;
    half_t* hout = gc.hout[g];
#pragma unroll
    for (int nt = 0; nt < 4; nt++) {
        float bb = b_gc[g * 64 + nt * 16 + cl];
        f32x4 c = {bb, bb, bb, bb};
        half8 B0 = *(const half8*)(wbase + ((nt * 2 + 0) * 64 + lane) * 8);
        half8 B1 = *(const half8*)(wbase + ((nt * 2 + 1) * 64 + lane) * 8);
        c = __builtin_amdgcn_mfma_f32_16x16x32_f16(A0, B0, c, 0, 0, 0);
        c = __builtin_amdgcn_mfma_f32_16x16x32_f16(A1, B1, c, 0, 0, 0);
#pragma unroll
        for (int r_ = 0; r_ < 4; r_++) {
            int node = tile * 16 + quad * 4 + r_;
            float x = c[r_];
            x = (x > 0.f) ? x : (__expf(x) - 1.f);
            hout[node * 128 + nt * 16 + cl] = (half_t)x;
        }
    }
}

// ---------------- semantic attention via MFMA: wave wv owns hidden slice [wv*32, wv*32+32).
// BATCH-4 double-buffered LDS staging (8KB/phase, all 4 waves issue 2 global_load_lds
// each); counted vmcnt(2) + raw s_barrier; barriers amortized 4x vs R11. Per-lane
// accumulation, one 64-lane reduce at the end. Same tile order -> bit-identical.
__global__ __launch_bounds__(256) void sem_att_kernel(SemArgs sa, float* __restrict__ wsum) {
    __shared__ half_t As[2][4][1024];   // 2 bufs x 4 tiles x 2KB
    __shared__ float s0[4], s1[4];
    int inst = blockIdx.x / SEMB;
    int blk  = blockIdx.x % SEMB;
    int t = threadIdx.x;
    int wv = t >> 6, lane = t & 63;
    int quad = lane >> 4, cl = lane & 15;
    const half_t* z = sa.z[inst];
    const float* W1 = sa.W1[inst];
    half8 Bf[2][2];
    float b1v[2], w2v[2];
#pragma unroll
    for (int u = 0; u < 2; u++) {
        int nt = wv * 2 + u;
        int n = nt * 16 + cl;
#pragma unroll
        for (int kh = 0; kh < 2; kh++) {
#pragma unroll
            for (int j = 0; j < 8; j++) {
                int k = kh * 32 + quad * 8 + j;
                Bf[u][kh][j] = (half_t)W1[k * HHID + n];
            }
        }
        b1v[u] = sa.b1[inst][nt * 16 + cl];
        w2v[u] = sa.w2[inst][nt * 16 + cl];
    }
    float local0 = 0.f, local1 = 0.f;
    int K = (6250 - blk + SEMB - 1) / SEMB;   // 12 or 13 tiles for this block
    int B = (K + 3) / 4;

    // wave wv stages tile k=4*bb+wv (2KB) via two 16B/lane global_load_lds.
    // LDS layout linear [n*64+j]; load q, lane l -> halfs q*512+l*8 = node q*8+(l>>3),
    // j=(l&7)*8 -- matches compute read As[.][i][cl*64 + quad*8].
#define SEM_STAGE(buf, bb) { \
    int k_ = 4 * (bb) + wv; \
    if (k_ < K) { \
        int tp_ = blk + k_ * SEMB; \
        int m_ = (tp_ >= 3125) ? 1 : 0; \
        int tm_ = tp_ - m_ * 3125; \
        int n_ = lane >> 3; \
        int j_ = (lane & 7) * 8; \
        const half_t* sA_ = z + (size_t)(tm_ * 16 + n_) * 128 + m_ * 64 + j_; \
        const half_t* sB_ = z + (size_t)(tm_ * 16 + 8 + n_) * 128 + m_ * 64 + j_; \
        __builtin_amdgcn_global_load_lds( \
            (const __attribute__((address_space(1))) unsigned int*)sA_, \
            (__attribute__((address_space(3))) unsigned int*)(&As[buf][wv][0]), 16, 0, 0); \
        __builtin_amdgcn_global_load_lds( \
            (const __attribute__((address_space(1))) unsigned int*)sB_, \
            (__attribute__((address_space(3))) unsigned int*)(&As[buf][wv][512]), 16, 0, 0); \
    } }

    int cur = 0;
    SEM_STAGE(0, 0);
    for (int b = 0; b < B; b++) {
        if (b + 1 < B) {
            SEM_STAGE(cur ^ 1, b + 1);
            asm volatile("s_waitcnt vmcnt(2)" ::: "memory");   // batch b done; b+1 in flight
        } else {
            asm volatile("s_waitcnt vmcnt(0)" ::: "memory");
        }
        __builtin_amdgcn_sched_barrier(0);
        __builtin_amdgcn_s_barrier();                          // raw: no vmcnt(0) drain
#pragma unroll
        for (int i = 0; i < 4; i++) {
            int k = 4 * b + i;
            if (k < K) {                                       // block-uniform
                int tile = blk + k * SEMB;
                const half_t* ar = &As[cur][i][cl * 64 + quad * 8];
                half8 A0 = *(const half8*)(ar);
                half8 A1 = *(const half8*)(ar + 32);
                float sumv = 0.f;
#pragma unroll
                for (int u = 0; u < 2; u++) {
                    f32x4 c = {0.f, 0.f, 0.f, 0.f};
                    c = __builtin_amdgcn_mfma_f32_16x16x32_f16(A0, Bf[u][0], c, 0, 0, 0);
                    c = __builtin_amdgcn_mfma_f32_16x16x32_f16(A1, Bf[u][1], c, 0, 0, 0);
#pragma unroll
                    for (int r = 0; r < 4; r++) {
                        float xv = c[r] + b1v[u];
                        float ev = __expf(2.f * xv);
                        float th = 1.f - 2.f * __builtin_amdgcn_rcpf(ev + 1.f);  // tanh
                        sumv += th * w2v[u];
                    }
                }
                if (tile < 3125) local0 += sumv; else local1 += sumv;
            }
        }
        __builtin_amdgcn_s_barrier();                          // readers done before re-stage
        cur ^= 1;
    }
#undef SEM_STAGE
    // single final 64-lane reduce
#pragma unroll
    for (int off = 32; off > 0; off >>= 1) {
        local0 += __shfl_down(local0, off);
        local1 += __shfl_down(local1, off);
    }
    if (lane == 0) { s0[wv] = local0; s1[wv] = local1; }
    __syncthreads();
    if (t == 0) {
        float a0 = s0[0] + s0[1] + s0[2] + s0[3];
        float a1 = s1[0] + s1[1] + s1[2] + s1[3];
        if (a0 != 0.f) atomicAdd(&wsum[inst * 2 + 0], a0);
        if (a1 != 0.f) atomicAdd(&wsum[inst * 2 + 1], a1);
    }
}

// ---------------- final combine: thread = 4 consecutive output cols
__global__ void combine_kernel(const half_t* __restrict__ ZU, const half_t* __restrict__ ZI,
                               const half_t* __restrict__ HU, const half_t* __restrict__ HI,
                               const float* __restrict__ wsum, float* __restrict__ out) {
    int gid = blockIdx.x * blockDim.x + threadIdx.x;
    if (gid >= (NU + NI) * 16) return;
    int node = gid >> 4;
    int c4 = (gid & 15) * 4;
    const half_t* zb; const half_t* hb;
    float wr0, wr1, wh0, wh1;
    int idx;
    if (node < NU) {
        zb = ZU; hb = HU; idx = node;
        wr0 = wsum[0]; wr1 = wsum[1]; wh0 = wsum[4]; wh1 = wsum[5];
    } else {
        zb = ZI; hb = HI; idx = node - NU;
        wr0 = wsum[2]; wr1 = wsum[3]; wh0 = wsum[6]; wh1 = wsum[7];
    }
    const float inv_n = 1.0f / 50000.0f;
    wr0 *= inv_n; wr1 *= inv_n; wh0 *= inv_n; wh1 *= inv_n;
    float m = fmaxf(wr0, wr1);
    float e0 = __expf(wr0 - m), e1 = __expf(wr1 - m);
    float br0 = e0 / (e0 + e1), br1 = e1 / (e0 + e1);
    m = fmaxf(wh0, wh1);
    e0 = __expf(wh0 - m); e1 = __expf(wh1 - m);
    float bh0 = e0 / (e0 + e1), bh1 = e1 / (e0 + e1);
    H4 z0, z1, h0, h1;
    z0.u = *(const uint2*)(zb + idx * 128 + c4);
    z1.u = *(const uint2*)(zb + idx * 128 + 64 + c4);
    h0.u = *(const uint2*)(hb + idx * 128 + c4);
    h1.u = *(const uint2*)(hb + idx * 128 + 64 + c4);
    float4 o;
    o.x = (float)z0.h[0] * br0 + (float)z1.h[0] * br1 + (float)h0.h[0] * bh0 + (float)h1.h[0] * bh1;
    o.y = (float)z0.h[1] * br0 + (float)z1.h[1] * br1 + (float)h0.h[1] * bh0 + (float)h1.h[1] * bh1;
    o.z = (float)z0.h[2] * br0 + (float)z1.h[2] * br1 + (float)h0.h[2] * bh0 + (float)h1.h[2] * bh1;
    o.w = (float)z0.h[3] * br0 + (float)z1.h[3] * br1 + (float)h0.h[3] * bh0 + (float)h1.h[3] * bh1;
    *(float4*)(out + node * 64 + c4) = o;
}

extern "C" void kernel_launch(void* const* d_in, const int* in_sizes, int n_in,
                              void* d_out, int out_size, void* d_ws, size_t ws_size,
                              hipStream_t stream) {
    const float* feat_user = (const float*)d_in[0];
    const float* feat_item = (const float*)d_in[1];
    const float* attn_l    = (const float*)d_in[2];
    const float* attn_r    = (const float*)d_in[3];
    const float* W_gc      = (const float*)d_in[4];
    const float* b_gc      = (const float*)d_in[5];
    const float* sa_rel_W1 = (const float*)d_in[6];
    const float* sa_rel_b1 = (const float*)d_in[7];
    const float* sa_rel_w2 = (const float*)d_in[8];
    const float* sa_u_W1   = (const float*)d_in[9];
    const float* sa_u_b1   = (const float*)d_in[10];
    const float* sa_u_w2   = (const float*)d_in[11];
    const float* sa_i_W1   = (const float*)d_in[12];
    const float* sa_i_b1   = (const float*)d_in[13];
    const float* sa_i_w2   = (const float*)d_in[14];
    const int* rel_u_src = (const int*)d_in[15];
    const int* rel_u_dst = (const int*)d_in[16];
    const int* rel_i_src = (const int*)d_in[17];
    const int* rel_i_dst = (const int*)d_in[18];
    const int* mp_u_src  = (const int*)d_in[19];
    const int* mp_u_dst  = (const int*)d_in[20];
    const int* mp_i_src  = (const int*)d_in[21];
    const int* mp_i_dst  = (const int*)d_in[22];

    // ---- workspace layout ----
    half_t* ZU   = (half_t*)d_ws;             // NN*128 fp16
    half_t* ZI   = ZU + NN * 128;
    half_t* HU   = ZI + NN * 128;
    half_t* HI   = HU + NN * 128;
    half_t* FBU  = HI + NN * 128;             // fp16 feat_user, NN*64
    half_t* FBI  = FBU + NN * 64;             // fp16 feat_item, NN*64
    float*  DI   = (float*)(FBI + NN * 64);   // 4*NN
    float*  DU   = DI + 4 * NN;               // 4*NN
    int2*   RD   = (int2*)(DU + 4 * NN);      // 8*NN {row_start, deg}
    int*    BUCKET = (int*)(RD + 8 * NN);     // 8*EE (packed w16|src)
    int*    CCNT = BUCKET + 8 * EE;           // 12*256 -- zeroed
    int*    DEG_SRC = CCNT + 12 * 256;        // 4*NN   -- fully written by degcnt
    float*  WSUM = (float*)(DEG_SRC + 4 * NN);// 8      -- zeroed
    half_t* W16  = (half_t*)(WSUM + 8);       // 4*4096 fp16 fragment-ordered W
    half_t* AGG  = W16 + 4 * 4096;            // 4*NN*64 fp16 GC aggregation buffer
    int*    COARSE = (int*)d_ws;              // 12*196*CAP ints (28.9MB), aliases ZU..HI; dead before agg

    hipMemsetAsync(CCNT, 0, (size_t)(12 * 256 + 4 * NN) * sizeof(int) + 8 * sizeof(float), stream);

    // ---- merged prep: fp16-cvt + dots + W fragments ----
    PrepArgs pa;
    pa.featI = feat_item; pa.featU = feat_user;
    pa.vi = Ptr4c{{ attn_l + 0 * DD, attn_l + 1 * DD, attn_r + 2 * DD, attn_r + 3 * DD }};
    pa.oi = Ptr4m{{ DI, DI + NI, DI + 2 * NI, DI + 3 * NI }};
    pa.vu = Ptr4c{{ attn_l + 2 * DD, attn_l + 3 * DD, attn_r + 0 * DD, attn_r + 1 * DD }};
    pa.ou = Ptr4m{{ DU, DU + NU, DU + 2 * NU, DU + 3 * NU }};
    pa.FBI = FBI; pa.FBU = FBU;
    pa.W_gc = W_gc; pa.W16 = W16;
    prep_kernel<<<6251, 256, 0, stream>>>(pa);

    // ---- CSR build (12 keyed images, atomic-free degree counting) ----
    EdgeArgs ea;
    ea.src[0] = rel_u_src;      ea.dst[0] = rel_u_dst;
    ea.src[1] = rel_u_src + EE; ea.dst[1] = rel_u_dst + EE;
    ea.src[2] = rel_i_src;      ea.dst[2] = rel_i_dst;
    ea.src[3] = rel_i_src + EE; ea.dst[3] = rel_i_dst + EE;
    ea.src[4] = mp_u_src;       ea.dst[4] = mp_u_dst;
    ea.src[5] = mp_u_src + EE;  ea.dst[5] = mp_u_dst + EE;
    ea.src[6] = mp_i_src;       ea.dst[6] = mp_i_dst;
    ea.src[7] = mp_i_src + EE;  ea.dst[7] = mp_i_dst + EE;

    part1_kernel<<<NIMG * TPG, P1T, 0, stream>>>(ea, CCNT, COARSE);
    degcnt_kernel<<<4 * NBKT, 256, 0, stream>>>(CCNT, COARSE, DEG_SRC);

    WArgs wa;
    wa.el[0] = DI;      wa.er[0] = DU + 2 * NU;
    wa.el[1] = DI + NI; wa.er[1] = DU + 3 * NU;
    wa.el[2] = DU;      wa.er[2] = DI + 2 * NI;
    wa.el[3] = DU + NU; wa.er[3] = DI + 3 * NI;
    wa.deg_src = DEG_SRC;
    part2_kernel<<<8 * NBKT, 256, 0, stream>>>(CCNT, COARSE, wa, BUCKET, RD);

    // ---- fused aggregation (2 column-halves x 8 graphs, octet-per-node) ----
    GatArgs ga;
    ga.fsrc[0] = FBI; ga.zout[0] = ZU;
    ga.fsrc[1] = FBI; ga.zout[1] = ZU + 64;
    ga.fsrc[2] = FBU; ga.zout[2] = ZI;
    ga.fsrc[3] = FBU; ga.zout[3] = ZI + 64;
    GcArgs gc;
    gc.feat[0] = FBU; gc.hout[0] = HU;
    gc.feat[1] = FBU; gc.hout[1] = HU + 64;
    gc.feat[2] = FBI; gc.hout[2] = HI;
    gc.feat[3] = FBI; gc.hout[3] = HI + 64;
    agg_kernel<<<16 * AGGB, 256, 0, stream>>>(ga, gc, AGG, RD, BUCKET);

    // ---- GC MFMA transform ----
    trans_kernel<<<4 * 782, 256, 0, stream>>>(gc, AGG, W16, b_gc);

    // ---- semantic attention (4 instances x SEMB blocks, batch-4 LDS pipeline) ----
    SemArgs sa;
    sa.z[0] = ZU; sa.W1[0] = sa_rel_W1; sa.b1[0] = sa_rel_b1; sa.w2[0] = sa_rel_w2;
    sa.z[1] = ZI; sa.W1[1] = sa_rel_W1; sa.b1[1] = sa_rel_b1; sa.w2[1] = sa_rel_w2;
    sa.z[2] = HU; sa.W1[2] = sa_u_W1;   sa.b1[2] = sa_u_b1;   sa.w2[2] = sa_u_w2;
    sa.z[3] = HI; sa.W1[3] = sa_i_W1;   sa.b1[3] = sa_i_b1;   sa.w2[3] = sa_i_w2;
    sem_att_kernel<<<4 * SEMB, 256, 0, stream>>>(sa, WSUM);

    // ---- combine ----
    combine_kernel<<<((NU + NI) * 16 + 255) / 256, 256, 0, stream>>>(ZU, ZI, HU, HI, WSUM, (float*)d_out);
}

// Round 13
// 329.636 us; speedup vs baseline: 1.1713x; 1.1713x over previous
//
#include <hip/hip_runtime.h>
#include <math.h>

#define NU 50000
#define NI 50000
#define NN 50000
#define DD 64
#define HHID 128
#define EE 500000
#define NEG_SLOPE 0.01f
#define NBKT 196           // coarse buckets of 256 nodes (key>>8)
#define CAP 3072           // capacity per (image,bucket) coarse region (mean 2551, +10 sigma)
#define TILE 8192          // tiles; tile_n always %4 == 0
#define TPG 62             // tiles per graph = ceil(500000/8192)
#define P1T 512            // build_kernel threads per block
#define NIMG 12            // 8 dst-keyed CSR images + 4 src-keyed count-only images
#define P1B (NIMG * TPG)   // 744 part1-style blocks (dispatched first)
#define AGGB 1563          // agg blocks per graph = ceil(50000/32)
#define SEMB 512           // sem_att blocks per instance

typedef _Float16 half_t;
typedef _Float16 half8 __attribute__((ext_vector_type(8)));
typedef float f32x4 __attribute__((ext_vector_type(4)));
union H4 { uint2 u; half_t h[4]; };
union H8 { uint4 u; half_t h[8]; };
union HS { half8 h; int i[4]; uint4 u; };
union HC { unsigned short us; half_t h; };

struct Ptr4c { const float* p[4]; };
struct Ptr4m { float*       p[4]; };
struct EdgeArgs { const int* src[8]; const int* dst[8]; };
struct GatArgs { const half_t* fsrc[4]; half_t* zout[4]; };
struct GcArgs  { const half_t* feat[4]; half_t* hout[4]; };
struct WArgs   { const float* el[4]; const float* er[4]; const int* deg_src; };
struct SemArgs { const half_t* z[4]; const float* W1[4]; const float* b1[4]; const float* w2[4]; };
struct PrepArgs {
    const float* featI; const float* featU;
    Ptr4c vi; Ptr4c vu; Ptr4m oi; Ptr4m ou;
    half_t* FBI; half_t* FBU;
    const float* W_gc; half_t* W16;
};

// ---------------- merged build: blocks [0,P1B) = part1 LDS counting-sort (12 keyed images),
// blocks [P1B, P1B+3126) = prep (fp16-cvt + dots; last block = W fragments). The two halves
// touch disjoint buffers (prep: FBI/FBU/DI/DU/W16; part1: edges->CCNT/COARSE), so they
// co-schedule and prep's HBM streaming hides under part1's LDS work.
__global__ __launch_bounds__(P1T) void build_kernel(EdgeArgs a, int* __restrict__ ccnt,
                                                    int* __restrict__ coarse, PrepArgs pa) {
    __shared__ int bc_cnt[256], bc_scan[256], bc_start[256], bc_cur[256], bc_gbase[256];
    __shared__ int stage[TILE];
    int t = threadIdx.x;
    if (blockIdx.x >= P1B) {
        // ---- prep half: 512 threads = 2 old 256-thread prep blocks ----
        int pb = blockIdx.x - P1B;
        if (pb == 3125) {
            if (t < 256) {
                int g = t >> 6;
                int lane = t & 63;
                int cl = lane & 15, quad = lane >> 4;
#pragma unroll
                for (int nt = 0; nt < 4; nt++) {
#pragma unroll
                    for (int kh = 0; kh < 2; kh++) {
                        H8 o;
#pragma unroll
                        for (int j = 0; j < 8; j++) {
                            int k = kh * 32 + quad * 8 + j;
                            int n = nt * 16 + cl;
                            o.h[j] = (half_t)pa.W_gc[g * 4096 + k * 64 + n];
                        }
                        *(uint4*)(pa.W16 + ((g * 8 + nt * 2 + kh) * 64 + lane) * 8) = o.u;
                    }
                }
            }
            return;
        }
        int ob = pb * 2 + (t >> 8);      // old prep block id in [0, 6250)
        int t256 = t & 255;
        const float* feat; Ptr4c vecs; Ptr4m outs; half_t* fb16; int bb;
        if (ob < 3125) { feat = pa.featI; vecs = pa.vi; outs = pa.oi; fb16 = pa.FBI; bb = ob; }
        else           { feat = pa.featU; vecs = pa.vu; outs = pa.ou; fb16 = pa.FBU; bb = ob - 3125; }
        int w = bb * 4 + (t256 >> 6);
        int lane = t256 & 63;
        int sub = lane >> 4, r = lane & 15;
        int node = w * 4 + sub;          // <= 49999 by construction
        float4 f = *(const float4*)(feat + node * DD + r * 4);
        H4 o16;
        o16.h[0] = (half_t)f.x; o16.h[1] = (half_t)f.y; o16.h[2] = (half_t)f.z; o16.h[3] = (half_t)f.w;
        *(uint2*)(fb16 + node * DD + r * 4) = o16.u;
#pragma unroll
        for (int j = 0; j < 4; j++) {
            float4 vv = *(const float4*)(vecs.p[j] + r * 4);
            float val = f.x * vv.x + f.y * vv.y + f.z * vv.z + f.w * vv.w;
            val += __shfl_down(val, 8);
            val += __shfl_down(val, 4);
            val += __shfl_down(val, 2);
            val += __shfl_down(val, 1);
            if (r == 0) outs.p[j][node] = val;
        }
        return;
    }
    // ---- part1 half: two-phase LDS counting-sort; NO global atomics ----
    int g = blockIdx.x / TPG;
    int tile = blockIdx.x % TPG;
    int e0 = tile * TILE;
    int tile_n = min(TILE, EE - e0);      // always % 4 == 0
    bool cnt_only = g >= 8;
    const int* gk = (cnt_only ? a.src[g - 4] : a.dst[g]) + e0;
    const int* gs = cnt_only ? gk : (a.src[g] + e0);
    if (t < 256) bc_cnt[t] = 0;
    __syncthreads();
    // phase A: key histogram (streaming int4)
    for (int pos = t * 4; pos < tile_n; pos += P1T * 4) {
        int4 k4 = *(const int4*)(gk + pos);
        atomicAdd(&bc_cnt[k4.x >> 8], 1);
        atomicAdd(&bc_cnt[k4.y >> 8], 1);
        atomicAdd(&bc_cnt[k4.z >> 8], 1);
        atomicAdd(&bc_cnt[k4.w >> 8], 1);
    }
    __syncthreads();
    if (t < 256) bc_scan[t] = bc_cnt[t];
    __syncthreads();
    for (int off = 1; off < 256; off <<= 1) {
        int v = (t < 256 && t >= off) ? bc_scan[t - off] : 0;
        __syncthreads();
        if (t < 256) bc_scan[t] += v;
        __syncthreads();
    }
    if (t < 256) {
        int st = bc_scan[t] - bc_cnt[t];
        bc_start[t] = st;
        bc_cur[t] = st;
        bc_gbase[t] = (t < NBKT && bc_cnt[t] > 0) ? atomicAdd(&ccnt[g * NBKT + t], bc_cnt[t]) : 0;
    }
    __syncthreads();
    // phase B: re-read keys (L2-hot), LDS scatter with packed bucket id
    for (int pos = t * 4; pos < tile_n; pos += P1T * 4) {
        int4 k4 = *(const int4*)(gk + pos);
        int4 s4;
        if (cnt_only) { s4 = make_int4(0, 0, 0, 0); }
        else          { s4 = *(const int4*)(gs + pos); }
        int b0 = k4.x >> 8, b1 = k4.y >> 8, b2 = k4.z >> 8, b3 = k4.w >> 8;
        int sl0 = atomicAdd(&bc_cur[b0], 1);
        int sl1 = atomicAdd(&bc_cur[b1], 1);
        int sl2 = atomicAdd(&bc_cur[b2], 1);
        int sl3 = atomicAdd(&bc_cur[b3], 1);
        stage[sl0] = s4.x | ((k4.x & 255) << 16) | (b0 << 24);
        stage[sl1] = s4.y | ((k4.y & 255) << 16) | (b1 << 24);
        stage[sl2] = s4.z | ((k4.z & 255) << 16) | (b2 << 24);
        stage[sl3] = s4.w | ((k4.w & 255) << 16) | (b3 << 24);
    }
    __syncthreads();
    // flush: bucket-sorted stage -> long contiguous global runs
    for (int j = t; j < tile_n; j += P1T) {
        int p = stage[j];
        int b = (unsigned)p >> 24;
        int pos = bc_gbase[b] + (j - bc_start[b]);
        if (pos < CAP) coarse[(g * NBKT + b) * CAP + pos] = p & 0x00FFFFFF;
    }
}

// ---------------- degree-count from src-keyed coarse buckets (images 8-11)
__global__ __launch_bounds__(256) void degcnt_kernel(const int* __restrict__ ccnt,
                                                     const int* __restrict__ coarse,
                                                     int* __restrict__ DEG_SRC) {
    __shared__ int cnt[256];
    int t = threadIdx.x;
    int g2 = blockIdx.x / NBKT;
    int b = blockIdx.x % NBKT;
    int img = 8 + g2;
    int n = min(ccnt[img * NBKT + b], CAP);
    cnt[t] = 0;
    __syncthreads();
    const int* pairs = coarse + (img * NBKT + b) * CAP;
    for (int i = t; i < n; i += 256) atomicAdd(&cnt[(pairs[i] >> 16) & 255], 1);
    __syncthreads();
    int v = (b << 8) + t;
    if (v < NN) DEG_SRC[g2 * NN + v] = cnt[t];
}

// ---------------- pass 2: per (graph,bucket) counting sort -> CSR with packed (w16<<16 | src)
__global__ __launch_bounds__(256) void part2_kernel(const int* __restrict__ ccnt,
                                                    const int* __restrict__ coarse,
                                                    WArgs wa,
                                                    int* __restrict__ bucket,
                                                    int2* __restrict__ RD) {
    __shared__ int sb[256];
    __shared__ int cnt5[256], off5[256], s2[256];
    __shared__ int ordered[CAP];
    int t = threadIdx.x;
    int g = blockIdx.x / NBKT;
    int b = blockIdx.x % NBKT;
    int ccv = (t < NBKT) ? min(ccnt[g * NBKT + t], CAP) : 0;
    sb[t] = ccv;
    cnt5[t] = 0;
    __syncthreads();
    for (int off = 1; off < 256; off <<= 1) {
        int vv = (t >= off) ? sb[t - off] : 0;
        __syncthreads();
        sb[t] += vv;
        __syncthreads();
    }
    int base = (b > 0) ? sb[b - 1] : 0;
    int n = sb[b] - base;
    int node0 = b << 8;
    const int* pairs = coarse + (g * NBKT + b) * CAP;
    for (int i = t; i < n; i += 256) atomicAdd(&cnt5[pairs[i] >> 16], 1);
    __syncthreads();
    int myc = cnt5[t];
    s2[t] = myc;
    __syncthreads();
    for (int off = 1; off < 256; off <<= 1) {
        int vv = (t >= off) ? s2[t - off] : 0;
        __syncthreads();
        s2[t] += vv;
        __syncthreads();
    }
    int ex = s2[t] - myc;
    off5[t] = ex;
    int v = node0 + t;
    if (v < NN) RD[g * NN + v] = make_int2(base + ex, myc);
    __syncthreads();
    int nm1 = n - 1;
    for (int ib = t; ib < n; ib += 1024) {
        int p[4];
#pragma unroll
        for (int u = 0; u < 4; u++) {
            int i = ib + u * 256;
            p[u] = pairs[(i < n) ? i : nm1];
        }
        float w[4];
        if (g < 4) {
            float a0[4], a1[4];
#pragma unroll
            for (int u = 0; u < 4; u++) a0[u] = wa.el[g][p[u] & 0xFFFF];
#pragma unroll
            for (int u = 0; u < 4; u++) a1[u] = wa.er[g][node0 + (p[u] >> 16)];
#pragma unroll
            for (int u = 0; u < 4; u++) {
                float e = a0[u] + a1[u];
                e = (e >= 0.f) ? e : NEG_SLOPE * e;
                w[u] = __expf(e);
            }
        } else {
            int dv[4];
#pragma unroll
            for (int u = 0; u < 4; u++) dv[u] = wa.deg_src[(g - 4) * NN + (p[u] & 0xFFFF)];
#pragma unroll
            for (int u = 0; u < 4; u++) w[u] = __builtin_amdgcn_rsqf((float)dv[u]);
        }
#pragma unroll
        for (int u = 0; u < 4; u++) {
            int i = ib + u * 256;
            if (i < n) {
                HC cv; cv.h = (half_t)w[u];
                int slot = atomicAdd(&off5[p[u] >> 16], 1);
                ordered[slot] = (p[u] & 0xFFFF) | ((int)cv.us << 16);
            }
        }
    }
    __syncthreads();
    int* bko = bucket + g * EE + base;
    for (int i = t; i < n; i += 256) bko[i] = ordered[i];
}

// ---------------- fused aggregation, octet-per-node (R11 full-row version; 66us, 3.16TB/s
// through the L2-miss path -- two restructure attempts regressed, treating as near-floor).
__global__ __launch_bounds__(256) void agg_kernel(GatArgs ga, GcArgs gc, half_t* __restrict__ AGG,
                                                  const int2* __restrict__ RD,
                                                  const int* __restrict__ bucket) {
    int g = blockIdx.x / AGGB;
    int nb = blockIdx.x % AGGB;
    int t = threadIdx.x;
    int wv = t >> 6, lane = t & 63;
    int q = lane >> 3, r = lane & 7;
    int v = nb * 32 + wv * 8 + q;
    bool vok = v < NN;
    int2 rd = RD[g * NN + (vok ? v : 0)];
    int start = rd.x;
    int dg = vok ? rd.y : 0;
    const int* bk = bucket + g * EE;
    const half_t* feat = (g < 4) ? ga.fsrc[g] : gc.feat[g - 4];
    int roff = r << 3;
    int obase = lane & 56;            // q*8 = base lane of this octet
    HS acc[4];
#pragma unroll
    for (int a = 0; a < 4; a++)
#pragma unroll
        for (int j = 0; j < 4; j++) acc[a].i[j] = 0;
    float s_l = 0.f;
    for (int b8 = 0; b8 < dg; b8 += 8) {          // octet-uniform trip count
        int rem = dg - b8;                        // octet-uniform
        int p = bk[start + b8 + ((r < rem) ? r : 0)];
#pragma unroll
        for (int j = 0; j < 8; j++) {
            if (j < rem) {                        // octet-uniform predicate
                int pj = __shfl(p, obase + j);    // source lane in same octet -> active
                HC wj; wj.us = (unsigned short)((unsigned)pj >> 16);
                s_l += (float)wj.h;
                HS row; row.u = *(const uint4*)(feat + (((pj & 0xFFFF) << 6) + roff));
                half_t wh = wj.h;
                half8 ws = {wh, wh, wh, wh, wh, wh, wh, wh};
                acc[j & 3].h += row.h * ws;
            }
        }
    }
    acc[0].h += acc[1].h;
    acc[2].h += acc[3].h;
    acc[0].h += acc[2].h;
    if (g < 4) {
        float inv = (dg > 0) ? __builtin_amdgcn_rcpf(s_l) : 0.f;
        H8 o;
#pragma unroll
        for (int i = 0; i < 8; i++) {
            float x = (float)acc[0].h[i] * inv;
            x = (x > 0.f) ? x : (__expf(x) - 1.f);
            o.h[i] = (half_t)x;
        }
        if (vok) *(uint4*)(ga.zout[g] + (v << 7) + roff) = o.u;
    } else {
        float niv = (dg > 0) ? __builtin_amdgcn_rsqf((float)dg) : 1.0f;
        H8 o;
#pragma unroll
        for (int i = 0; i < 8; i++) o.h[i] = (half_t)((float)acc[0].h[i] * niv);
        if (vok) *(uint4*)(AGG + (((g - 4) * NN + v) << 6) + roff) = o.u;
    }
}

// ---------------- GC transform: wave = 16-node tile, A from AGG, B = W16 fragments, 8 MFMA
__global__ __launch_bounds__(256) void trans_kernel(GcArgs gc, const half_t* __restrict__ AGG,
                                                    const half_t* __restrict__ W16,
                                                    const float* __restrict__ b_gc) {
    int t = threadIdx.x;
    int wv = t >> 6, lane = t & 63;
    int g = blockIdx.x / 782;
    int tile = (blockIdx.x % 782) * 4 + wv;
    if (tile >= 3125) return;
    int cl = lane & 15, quad = lane >> 4;
    const half_t* ab = AGG + ((g * NN + tile * 16 + cl) << 6);
    half8 A0 = *(const half8*)(ab + quad * 8);
    half8 A1 = *(const half8*)(ab + 32 + quad * 8);
    const half_t* wbase = W16 + g * 8 * 64 * 8;
    half_t* hout = gc.hout[g];
#pragma unroll
    for (int nt = 0; nt < 4; nt++) {
        float bb = b_gc[g * 64 + nt * 16 + cl];
        f32x4 c = {bb, bb, bb, bb};
        half8 B0 = *(const half8*)(wbase + ((nt * 2 + 0) * 64 + lane) * 8);
        half8 B1 = *(const half8*)(wbase + ((nt * 2 + 1) * 64 + lane) * 8);
        c = __builtin_amdgcn_mfma_f32_16x16x32_f16(A0, B0, c, 0, 0, 0);
        c = __builtin_amdgcn_mfma_f32_16x16x32_f16(A1, B1, c, 0, 0, 0);
#pragma unroll
        for (int r_ = 0; r_ < 4; r_++) {
            int node = tile * 16 + quad * 4 + r_;
            float x = c[r_];
            x = (x > 0.f) ? x : (__expf(x) - 1.f);
            hout[node * 128 + nt * 16 + cl] = (half_t)x;
        }
    }
}

// ---------------- semantic attention via MFMA: wave wv owns hidden slice [wv*32, wv*32+32).
// BATCH-4 double-buffered LDS staging; counted vmcnt(2) + raw s_barrier. Per-lane
// accumulation, one 64-lane reduce at the end.
__global__ __launch_bounds__(256) void sem_att_kernel(SemArgs sa, float* __restrict__ wsum) {
    __shared__ half_t As[2][4][1024];   // 2 bufs x 4 tiles x 2KB
    __shared__ float s0[4], s1[4];
    int inst = blockIdx.x / SEMB;
    int blk  = blockIdx.x % SEMB;
    int t = threadIdx.x;
    int wv = t >> 6, lane = t & 63;
    int quad = lane >> 4, cl = lane & 15;
    const half_t* z = sa.z[inst];
    const float* W1 = sa.W1[inst];
    half8 Bf[2][2];
    float b1v[2], w2v[2];
#pragma unroll
    for (int u = 0; u < 2; u++) {
        int nt = wv * 2 + u;
        int n = nt * 16 + cl;
#pragma unroll
        for (int kh = 0; kh < 2; kh++) {
#pragma unroll
            for (int j = 0; j < 8; j++) {
                int k = kh * 32 + quad * 8 + j;
                Bf[u][kh][j] = (half_t)W1[k * HHID + n];
            }
        }
        b1v[u] = sa.b1[inst][nt * 16 + cl];
        w2v[u] = sa.w2[inst][nt * 16 + cl];
    }
    float local0 = 0.f, local1 = 0.f;
    int K = (6250 - blk + SEMB - 1) / SEMB;   // 12 or 13 tiles for this block
    int B = (K + 3) / 4;

#define SEM_STAGE(buf, bb) { \
    int k_ = 4 * (bb) + wv; \
    if (k_ < K) { \
        int tp_ = blk + k_ * SEMB; \
        int m_ = (tp_ >= 3125) ? 1 : 0; \
        int tm_ = tp_ - m_ * 3125; \
        int n_ = lane >> 3; \
        int j_ = (lane & 7) * 8; \
        const half_t* sA_ = z + (size_t)(tm_ * 16 + n_) * 128 + m_ * 64 + j_; \
        const half_t* sB_ = z + (size_t)(tm_ * 16 + 8 + n_) * 128 + m_ * 64 + j_; \
        __builtin_amdgcn_global_load_lds( \
            (const __attribute__((address_space(1))) unsigned int*)sA_, \
            (__attribute__((address_space(3))) unsigned int*)(&As[buf][wv][0]), 16, 0, 0); \
        __builtin_amdgcn_global_load_lds( \
            (const __attribute__((address_space(1))) unsigned int*)sB_, \
            (__attribute__((address_space(3))) unsigned int*)(&As[buf][wv][512]), 16, 0, 0); \
    } }

    int cur = 0;
    SEM_STAGE(0, 0);
    for (int b = 0; b < B; b++) {
        if (b + 1 < B) {
            SEM_STAGE(cur ^ 1, b + 1);
            asm volatile("s_waitcnt vmcnt(2)" ::: "memory");   // batch b done; b+1 in flight
        } else {
            asm volatile("s_waitcnt vmcnt(0)" ::: "memory");
        }
        __builtin_amdgcn_sched_barrier(0);
        __builtin_amdgcn_s_barrier();                          // raw: no vmcnt(0) drain
#pragma unroll
        for (int i = 0; i < 4; i++) {
            int k = 4 * b + i;
            if (k < K) {                                       // block-uniform
                int tile = blk + k * SEMB;
                const half_t* ar = &As[cur][i][cl * 64 + quad * 8];
                half8 A0 = *(const half8*)(ar);
                half8 A1 = *(const half8*)(ar + 32);
                float sumv = 0.f;
#pragma unroll
                for (int u = 0; u < 2; u++) {
                    f32x4 c = {0.f, 0.f, 0.f, 0.f};
                    c = __builtin_amdgcn_mfma_f32_16x16x32_f16(A0, Bf[u][0], c, 0, 0, 0);
                    c = __builtin_amdgcn_mfma_f32_16x16x32_f16(A1, Bf[u][1], c, 0, 0, 0);
#pragma unroll
                    for (int r = 0; r < 4; r++) {
                        float xv = c[r] + b1v[u];
                        float ev = __expf(2.f * xv);
                        float th = 1.f - 2.f * __builtin_amdgcn_rcpf(ev + 1.f);  // tanh
                        sumv += th * w2v[u];
                    }
                }
                if (tile < 3125) local0 += sumv; else local1 += sumv;
            }
        }
        __builtin_amdgcn_s_barrier();                          // readers done before re-stage
        cur ^= 1;
    }
#undef SEM_STAGE
#pragma unroll
    for (int off = 32; off > 0; off >>= 1) {
        local0 += __shfl_down(local0, off);
        local1 += __shfl_down(local1, off);
    }
    if (lane == 0) { s0[wv] = local0; s1[wv] = local1; }
    __syncthreads();
    if (t == 0) {
        float a0 = s0[0] + s0[1] + s0[2] + s0[3];
        float a1 = s1[0] + s1[1] + s1[2] + s1[3];
        if (a0 != 0.f) atomicAdd(&wsum[inst * 2 + 0], a0);
        if (a1 != 0.f) atomicAdd(&wsum[inst * 2 + 1], a1);
    }
}

// ---------------- final combine: thread = 4 consecutive output cols
__global__ void combine_kernel(const half_t* __restrict__ ZU, const half_t* __restrict__ ZI,
                               const half_t* __restrict__ HU, const half_t* __restrict__ HI,
                               const float* __restrict__ wsum, float* __restrict__ out) {
    int gid = blockIdx.x * blockDim.x + threadIdx.x;
    if (gid >= (NU + NI) * 16) return;
    int node = gid >> 4;
    int c4 = (gid & 15) * 4;
    const half_t* zb; const half_t* hb;
    float wr0, wr1, wh0, wh1;
    int idx;
    if (node < NU) {
        zb = ZU; hb = HU; idx = node;
        wr0 = wsum[0]; wr1 = wsum[1]; wh0 = wsum[4]; wh1 = wsum[5];
    } else {
        zb = ZI; hb = HI; idx = node - NU;
        wr0 = wsum[2]; wr1 = wsum[3]; wh0 = wsum[6]; wh1 = wsum[7];
    }
    const float inv_n = 1.0f / 50000.0f;
    wr0 *= inv_n; wr1 *= inv_n; wh0 *= inv_n; wh1 *= inv_n;
    float m = fmaxf(wr0, wr1);
    float e0 = __expf(wr0 - m), e1 = __expf(wr1 - m);
    float br0 = e0 / (e0 + e1), br1 = e1 / (e0 + e1);
    m = fmaxf(wh0, wh1);
    e0 = __expf(wh0 - m); e1 = __expf(wh1 - m);
    float bh0 = e0 / (e0 + e1), bh1 = e1 / (e0 + e1);
    H4 z0, z1, h0, h1;
    z0.u = *(const uint2*)(zb + idx * 128 + c4);
    z1.u = *(const uint2*)(zb + idx * 128 + 64 + c4);
    h0.u = *(const uint2*)(hb + idx * 128 + c4);
    h1.u = *(const uint2*)(hb + idx * 128 + 64 + c4);
    float4 o;
    o.x = (float)z0.h[0] * br0 + (float)z1.h[0] * br1 + (float)h0.h[0] * bh0 + (float)h1.h[0] * bh1;
    o.y = (float)z0.h[1] * br0 + (float)z1.h[1] * br1 + (float)h0.h[1] * bh0 + (float)h1.h[1] * bh1;
    o.z = (float)z0.h[2] * br0 + (float)z1.h[2] * br1 + (float)h0.h[2] * bh0 + (float)h1.h[2] * bh1;
    o.w = (float)z0.h[3] * br0 + (float)z1.h[3] * br1 + (float)h0.h[3] * bh0 + (float)h1.h[3] * bh1;
    *(float4*)(out + node * 64 + c4) = o;
}

extern "C" void kernel_launch(void* const* d_in, const int* in_sizes, int n_in,
                              void* d_out, int out_size, void* d_ws, size_t ws_size,
                              hipStream_t stream) {
    const float* feat_user = (const float*)d_in[0];
    const float* feat_item = (const float*)d_in[1];
    const float* attn_l    = (const float*)d_in[2];
    const float* attn_r    = (const float*)d_in[3];
    const float* W_gc      = (const float*)d_in[4];
    const float* b_gc      = (const float*)d_in[5];
    const float* sa_rel_W1 = (const float*)d_in[6];
    const float* sa_rel_b1 = (const float*)d_in[7];
    const float* sa_rel_w2 = (const float*)d_in[8];
    const float* sa_u_W1   = (const float*)d_in[9];
    const float* sa_u_b1   = (const float*)d_in[10];
    const float* sa_u_w2   = (const float*)d_in[11];
    const float* sa_i_W1   = (const float*)d_in[12];
    const float* sa_i_b1   = (const float*)d_in[13];
    const float* sa_i_w2   = (const float*)d_in[14];
    const int* rel_u_src = (const int*)d_in[15];
    const int* rel_u_dst = (const int*)d_in[16];
    const int* rel_i_src = (const int*)d_in[17];
    const int* rel_i_dst = (const int*)d_in[18];
    const int* mp_u_src  = (const int*)d_in[19];
    const int* mp_u_dst  = (const int*)d_in[20];
    const int* mp_i_src  = (const int*)d_in[21];
    const int* mp_i_dst  = (const int*)d_in[22];

    // ---- workspace layout ----
    half_t* ZU   = (half_t*)d_ws;             // NN*128 fp16
    half_t* ZI   = ZU + NN * 128;
    half_t* HU   = ZI + NN * 128;
    half_t* HI   = HU + NN * 128;
    half_t* FBU  = HI + NN * 128;             // fp16 feat_user, NN*64
    half_t* FBI  = FBU + NN * 64;             // fp16 feat_item, NN*64
    float*  DI   = (float*)(FBI + NN * 64);   // 4*NN
    float*  DU   = DI + 4 * NN;               // 4*NN
    int2*   RD   = (int2*)(DU + 4 * NN);      // 8*NN {row_start, deg}
    int*    BUCKET = (int*)(RD + 8 * NN);     // 8*EE (packed w16|src)
    int*    CCNT = BUCKET + 8 * EE;           // 12*256 -- zeroed
    int*    DEG_SRC = CCNT + 12 * 256;        // 4*NN   -- fully written by degcnt
    float*  WSUM = (float*)(DEG_SRC + 4 * NN);// 8      -- zeroed
    half_t* W16  = (half_t*)(WSUM + 8);       // 4*4096 fp16 fragment-ordered W
    half_t* AGG  = W16 + 4 * 4096;            // 4*NN*64 fp16 GC aggregation buffer
    int*    COARSE = (int*)d_ws;              // 12*196*CAP ints (28.9MB), aliases ZU..HI; dead before agg

    hipMemsetAsync(CCNT, 0, (size_t)(12 * 256 + 4 * NN) * sizeof(int) + 8 * sizeof(float), stream);

    // ---- merged CSR-partition + prep (independent halves, co-scheduled) ----
    PrepArgs pa;
    pa.featI = feat_item; pa.featU = feat_user;
    pa.vi = Ptr4c{{ attn_l + 0 * DD, attn_l + 1 * DD, attn_r + 2 * DD, attn_r + 3 * DD }};
    pa.oi = Ptr4m{{ DI, DI + NI, DI + 2 * NI, DI + 3 * NI }};
    pa.vu = Ptr4c{{ attn_l + 2 * DD, attn_l + 3 * DD, attn_r + 0 * DD, attn_r + 1 * DD }};
    pa.ou = Ptr4m{{ DU, DU + NU, DU + 2 * NU, DU + 3 * NU }};
    pa.FBI = FBI; pa.FBU = FBU;
    pa.W_gc = W_gc; pa.W16 = W16;

    EdgeArgs ea;
    ea.src[0] = rel_u_src;      ea.dst[0] = rel_u_dst;
    ea.src[1] = rel_u_src + EE; ea.dst[1] = rel_u_dst + EE;
    ea.src[2] = rel_i_src;      ea.dst[2] = rel_i_dst;
    ea.src[3] = rel_i_src + EE; ea.dst[3] = rel_i_dst + EE;
    ea.src[4] = mp_u_src;       ea.dst[4] = mp_u_dst;
    ea.src[5] = mp_u_src + EE;  ea.dst[5] = mp_u_dst + EE;
    ea.src[6] = mp_i_src;       ea.dst[6] = mp_i_dst;
    ea.src[7] = mp_i_src + EE;  ea.dst[7] = mp_i_dst + EE;

    build_kernel<<<P1B + 3126, P1T, 0, stream>>>(ea, CCNT, COARSE, pa);
    degcnt_kernel<<<4 * NBKT, 256, 0, stream>>>(CCNT, COARSE, DEG_SRC);

    WArgs wa;
    wa.el[0] = DI;      wa.er[0] = DU + 2 * NU;
    wa.el[1] = DI + NI; wa.er[1] = DU + 3 * NU;
    wa.el[2] = DU;      wa.er[2] = DI + 2 * NI;
    wa.el[3] = DU + NU; wa.er[3] = DI + 3 * NI;
    wa.deg_src = DEG_SRC;
    part2_kernel<<<8 * NBKT, 256, 0, stream>>>(CCNT, COARSE, wa, BUCKET, RD);

    // ---- fused aggregation (8 graphs, octet-per-node, full-row) ----
    GatArgs ga;
    ga.fsrc[0] = FBI; ga.zout[0] = ZU;
    ga.fsrc[1] = FBI; ga.zout[1] = ZU + 64;
    ga.fsrc[2] = FBU; ga.zout[2] = ZI;
    ga.fsrc[3] = FBU; ga.zout[3] = ZI + 64;
    GcArgs gc;
    gc.feat[0] = FBU; gc.hout[0] = HU;
    gc.feat[1] = FBU; gc.hout[1] = HU + 64;
    gc.feat[2] = FBI; gc.hout[2] = HI;
    gc.feat[3] = FBI; gc.hout[3] = HI + 64;
    agg_kernel<<<8 * AGGB, 256, 0, stream>>>(ga, gc, AGG, RD, BUCKET);

    // ---- GC MFMA transform ----
    trans_kernel<<<4 * 782, 256, 0, stream>>>(gc, AGG, W16, b_gc);

    // ---- semantic attention (4 instances x SEMB blocks, batch-4 LDS pipeline) ----
    SemArgs sa;
    sa.z[0] = ZU; sa.W1[0] = sa_rel_W1; sa.b1[0] = sa_rel_b1; sa.w2[0] = sa_rel_w2;
    sa.z[1] = ZI; sa.W1[1] = sa_rel_W1; sa.b1[1] = sa_rel_b1; sa.w2[1] = sa_rel_w2;
    sa.z[2] = HU; sa.W1[2] = sa_u_W1;   sa.b1[2] = sa_u_b1;   sa.w2[2] = sa_u_w2;
    sa.z[3] = HI; sa.W1[3] = sa_i_W1;   sa.b1[3] = sa_i_b1;   sa.w2[3] = sa_i_w2;
    sem_att_kernel<<<4 * SEMB, 256, 0, stream>>>(sa, WSUM);

    // ---- combine ----
    combine_kernel<<<((NU + NI) * 16 + 255) / 256, 256, 0, stream>>>(ZU, ZI, HU, HI, WSUM, (float*)d_out);
}

// Round 14
// 320.595 us; speedup vs baseline: 1.2044x; 1.0282x over previous
//
#include <hip/hip_runtime.h>
#include <math.h>

#define NU 50000
#define NI 50000
#define NN 50000
#define DD 64
#define HHID 128
#define EE 500000
#define NEG_SLOPE 0.01f
#define NBKT 196           // coarse buckets of 256 nodes (key>>8)
#define CAP 3072           // capacity per (image,bucket) coarse region (mean 2551, +10 sigma)
#define TILE 8192          // tiles; tile_n always %4 == 0
#define TPG 62             // tiles per graph = ceil(500000/8192)
#define P1T 512            // build_kernel threads per block
#define NIMG 12            // 8 dst-keyed CSR images + 4 src-keyed count-only images
#define P1B (NIMG * TPG)   // 744 part1-style blocks (dispatched first)
#define AGGB 1563          // agg blocks per graph = ceil(50000/32)
#define SEMB 512           // sem_att blocks per instance

typedef _Float16 half_t;
typedef _Float16 half8 __attribute__((ext_vector_type(8)));
typedef float f32x4 __attribute__((ext_vector_type(4)));
union H4 { uint2 u; half_t h[4]; };
union H8 { uint4 u; half_t h[8]; };
union HS { half8 h; int i[4]; uint4 u; };
union HC { unsigned short us; half_t h; };

struct Ptr4c { const float* p[4]; };
struct Ptr4m { float*       p[4]; };
struct EdgeArgs { const int* src[8]; const int* dst[8]; };
struct GatArgs { const half_t* fsrc[4]; half_t* zout[4]; };
struct GcArgs  { const half_t* feat[4]; half_t* hout[4]; };
struct WArgs   { const float* el[4]; const float* er[4]; const int* deg_src; };
struct SemArgs { const half_t* z[4]; const float* W1[4]; const float* b1[4]; const float* w2[4]; };
struct PrepArgs {
    const float* featI; const float* featU;
    Ptr4c vi; Ptr4c vu; Ptr4m oi; Ptr4m ou;
    half_t* FBI; half_t* FBU;
    const float* W_gc; half_t* W16;
};

// ---------------- merged build: blocks [0,P1B) = part1 LDS counting-sort (12 keyed images),
// blocks [P1B, P1B+3126) = prep (fp16-cvt + dots; last block = W fragments).
__global__ __launch_bounds__(P1T) void build_kernel(EdgeArgs a, int* __restrict__ ccnt,
                                                    int* __restrict__ coarse, PrepArgs pa) {
    __shared__ int bc_cnt[256], bc_scan[256], bc_start[256], bc_cur[256], bc_gbase[256];
    __shared__ int stage[TILE];
    int t = threadIdx.x;
    if (blockIdx.x >= P1B) {
        // ---- prep half: 512 threads = 2 old 256-thread prep blocks ----
        int pb = blockIdx.x - P1B;
        if (pb == 3125) {
            if (t < 256) {
                int g = t >> 6;
                int lane = t & 63;
                int cl = lane & 15, quad = lane >> 4;
#pragma unroll
                for (int nt = 0; nt < 4; nt++) {
#pragma unroll
                    for (int kh = 0; kh < 2; kh++) {
                        H8 o;
#pragma unroll
                        for (int j = 0; j < 8; j++) {
                            int k = kh * 32 + quad * 8 + j;
                            int n = nt * 16 + cl;
                            o.h[j] = (half_t)pa.W_gc[g * 4096 + k * 64 + n];
                        }
                        *(uint4*)(pa.W16 + ((g * 8 + nt * 2 + kh) * 64 + lane) * 8) = o.u;
                    }
                }
            }
            return;
        }
        int ob = pb * 2 + (t >> 8);      // old prep block id in [0, 6250)
        int t256 = t & 255;
        const float* feat; Ptr4c vecs; Ptr4m outs; half_t* fb16; int bb;
        if (ob < 3125) { feat = pa.featI; vecs = pa.vi; outs = pa.oi; fb16 = pa.FBI; bb = ob; }
        else           { feat = pa.featU; vecs = pa.vu; outs = pa.ou; fb16 = pa.FBU; bb = ob - 3125; }
        int w = bb * 4 + (t256 >> 6);
        int lane = t256 & 63;
        int sub = lane >> 4, r = lane & 15;
        int node = w * 4 + sub;          // <= 49999 by construction
        float4 f = *(const float4*)(feat + node * DD + r * 4);
        H4 o16;
        o16.h[0] = (half_t)f.x; o16.h[1] = (half_t)f.y; o16.h[2] = (half_t)f.z; o16.h[3] = (half_t)f.w;
        *(uint2*)(fb16 + node * DD + r * 4) = o16.u;
#pragma unroll
        for (int j = 0; j < 4; j++) {
            float4 vv = *(const float4*)(vecs.p[j] + r * 4);
            float val = f.x * vv.x + f.y * vv.y + f.z * vv.z + f.w * vv.w;
            val += __shfl_down(val, 8);
            val += __shfl_down(val, 4);
            val += __shfl_down(val, 2);
            val += __shfl_down(val, 1);
            if (r == 0) outs.p[j][node] = val;
        }
        return;
    }
    // ---- part1 half: two-phase LDS counting-sort; NO global atomics ----
    int g = blockIdx.x / TPG;
    int tile = blockIdx.x % TPG;
    int e0 = tile * TILE;
    int tile_n = min(TILE, EE - e0);      // always % 4 == 0
    bool cnt_only = g >= 8;
    const int* gk = (cnt_only ? a.src[g - 4] : a.dst[g]) + e0;
    const int* gs = cnt_only ? gk : (a.src[g] + e0);
    if (t < 256) bc_cnt[t] = 0;
    __syncthreads();
    // phase A: key histogram (streaming int4)
    for (int pos = t * 4; pos < tile_n; pos += P1T * 4) {
        int4 k4 = *(const int4*)(gk + pos);
        atomicAdd(&bc_cnt[k4.x >> 8], 1);
        atomicAdd(&bc_cnt[k4.y >> 8], 1);
        atomicAdd(&bc_cnt[k4.z >> 8], 1);
        atomicAdd(&bc_cnt[k4.w >> 8], 1);
    }
    __syncthreads();
    if (t < 256) bc_scan[t] = bc_cnt[t];
    __syncthreads();
    for (int off = 1; off < 256; off <<= 1) {
        int v = (t < 256 && t >= off) ? bc_scan[t - off] : 0;
        __syncthreads();
        if (t < 256) bc_scan[t] += v;
        __syncthreads();
    }
    if (t < 256) {
        int st = bc_scan[t] - bc_cnt[t];
        bc_start[t] = st;
        bc_cur[t] = st;
        bc_gbase[t] = (t < NBKT && bc_cnt[t] > 0) ? atomicAdd(&ccnt[g * NBKT + t], bc_cnt[t]) : 0;
    }
    __syncthreads();
    // phase B: re-read keys (L2-hot), LDS scatter with packed bucket id
    for (int pos = t * 4; pos < tile_n; pos += P1T * 4) {
        int4 k4 = *(const int4*)(gk + pos);
        int4 s4;
        if (cnt_only) { s4 = make_int4(0, 0, 0, 0); }
        else          { s4 = *(const int4*)(gs + pos); }
        int b0 = k4.x >> 8, b1 = k4.y >> 8, b2 = k4.z >> 8, b3 = k4.w >> 8;
        int sl0 = atomicAdd(&bc_cur[b0], 1);
        int sl1 = atomicAdd(&bc_cur[b1], 1);
        int sl2 = atomicAdd(&bc_cur[b2], 1);
        int sl3 = atomicAdd(&bc_cur[b3], 1);
        stage[sl0] = s4.x | ((k4.x & 255) << 16) | (b0 << 24);
        stage[sl1] = s4.y | ((k4.y & 255) << 16) | (b1 << 24);
        stage[sl2] = s4.z | ((k4.z & 255) << 16) | (b2 << 24);
        stage[sl3] = s4.w | ((k4.w & 255) << 16) | (b3 << 24);
    }
    __syncthreads();
    // flush: bucket-sorted stage -> long contiguous global runs
    for (int j = t; j < tile_n; j += P1T) {
        int p = stage[j];
        int b = (unsigned)p >> 24;
        int pos = bc_gbase[b] + (j - bc_start[b]);
        if (pos < CAP) coarse[(g * NBKT + b) * CAP + pos] = p & 0x00FFFFFF;
    }
}

// ---------------- degree-count from src-keyed coarse buckets (images 8-11)
__global__ __launch_bounds__(256) void degcnt_kernel(const int* __restrict__ ccnt,
                                                     const int* __restrict__ coarse,
                                                     int* __restrict__ DEG_SRC) {
    __shared__ int cnt[256];
    int t = threadIdx.x;
    int g2 = blockIdx.x / NBKT;
    int b = blockIdx.x % NBKT;
    int img = 8 + g2;
    int n = min(ccnt[img * NBKT + b], CAP);
    cnt[t] = 0;
    __syncthreads();
    const int* pairs = coarse + (img * NBKT + b) * CAP;
    for (int i = t; i < n; i += 256) atomicAdd(&cnt[(pairs[i] >> 16) & 255], 1);
    __syncthreads();
    int v = (b << 8) + t;
    if (v < NN) DEG_SRC[g2 * NN + v] = cnt[t];
}

// ---------------- pass 2: per (graph,bucket) counting sort -> CSR with packed (w16<<16 | src)
__global__ __launch_bounds__(256) void part2_kernel(const int* __restrict__ ccnt,
                                                    const int* __restrict__ coarse,
                                                    WArgs wa,
                                                    int* __restrict__ bucket,
                                                    int2* __restrict__ RD) {
    __shared__ int sb[256];
    __shared__ int cnt5[256], off5[256], s2[256];
    __shared__ int ordered[CAP];
    int t = threadIdx.x;
    int g = blockIdx.x / NBKT;
    int b = blockIdx.x % NBKT;
    int ccv = (t < NBKT) ? min(ccnt[g * NBKT + t], CAP) : 0;
    sb[t] = ccv;
    cnt5[t] = 0;
    __syncthreads();
    for (int off = 1; off < 256; off <<= 1) {
        int vv = (t >= off) ? sb[t - off] : 0;
        __syncthreads();
        sb[t] += vv;
        __syncthreads();
    }
    int base = (b > 0) ? sb[b - 1] : 0;
    int n = sb[b] - base;
    int node0 = b << 8;
    const int* pairs = coarse + (g * NBKT + b) * CAP;
    for (int i = t; i < n; i += 256) atomicAdd(&cnt5[pairs[i] >> 16], 1);
    __syncthreads();
    int myc = cnt5[t];
    s2[t] = myc;
    __syncthreads();
    for (int off = 1; off < 256; off <<= 1) {
        int vv = (t >= off) ? s2[t - off] : 0;
        __syncthreads();
        s2[t] += vv;
        __syncthreads();
    }
    int ex = s2[t] - myc;
    off5[t] = ex;
    int v = node0 + t;
    if (v < NN) RD[g * NN + v] = make_int2(base + ex, myc);
    __syncthreads();
    int nm1 = n - 1;
    for (int ib = t; ib < n; ib += 1024) {
        int p[4];
#pragma unroll
        for (int u = 0; u < 4; u++) {
            int i = ib + u * 256;
            p[u] = pairs[(i < n) ? i : nm1];
        }
        float w[4];
        if (g < 4) {
            float a0[4], a1[4];
#pragma unroll
            for (int u = 0; u < 4; u++) a0[u] = wa.el[g][p[u] & 0xFFFF];
#pragma unroll
            for (int u = 0; u < 4; u++) a1[u] = wa.er[g][node0 + (p[u] >> 16)];
#pragma unroll
            for (int u = 0; u < 4; u++) {
                float e = a0[u] + a1[u];
                e = (e >= 0.f) ? e : NEG_SLOPE * e;
                w[u] = __expf(e);
            }
        } else {
            int dv[4];
#pragma unroll
            for (int u = 0; u < 4; u++) dv[u] = wa.deg_src[(g - 4) * NN + (p[u] & 0xFFFF)];
#pragma unroll
            for (int u = 0; u < 4; u++) w[u] = __builtin_amdgcn_rsqf((float)dv[u]);
        }
#pragma unroll
        for (int u = 0; u < 4; u++) {
            int i = ib + u * 256;
            if (i < n) {
                HC cv; cv.h = (half_t)w[u];
                int slot = atomicAdd(&off5[p[u] >> 16], 1);
                ordered[slot] = (p[u] & 0xFFFF) | ((int)cv.us << 16);
            }
        }
    }
    __syncthreads();
    int* bko = bucket + g * EE + base;
    for (int i = t; i < n; i += 256) bko[i] = ordered[i];
}

// ---------------- fused aggregation + GC transform, octet-per-node.
// Gather loop untouched (near-floor: 66us, 3.16TB/s L2-miss path). For g>=4 the epilogue
// stages the block's 32x64 fp16 aggregate in LDS (same rounding as the old AGG round-trip
// -> bit-identical), then the 4 waves do the 8 MFMAs (2 waves/16-node tile, 2 nt each)
// + bias + elu + hout store -- the old trans_kernel, minus 51MB of AGG HBM traffic.
__global__ __launch_bounds__(256) void agg_kernel(GatArgs ga, GcArgs gc,
                                                  const half_t* __restrict__ W16,
                                                  const float* __restrict__ b_gc,
                                                  const int2* __restrict__ RD,
                                                  const int* __restrict__ bucket) {
    __shared__ half_t AS[32][64];     // 4KB: 32 nodes x 64 cols
    int g = blockIdx.x / AGGB;
    int nb = blockIdx.x % AGGB;
    int t = threadIdx.x;
    int wv = t >> 6, lane = t & 63;
    int q = lane >> 3, r = lane & 7;
    int v = nb * 32 + wv * 8 + q;
    bool vok = v < NN;
    int2 rd = RD[g * NN + (vok ? v : 0)];
    int start = rd.x;
    int dg = vok ? rd.y : 0;
    const int* bk = bucket + g * EE;
    const half_t* feat = (g < 4) ? ga.fsrc[g] : gc.feat[g - 4];
    int roff = r << 3;
    int obase = lane & 56;            // q*8 = base lane of this octet
    HS acc[4];
#pragma unroll
    for (int a = 0; a < 4; a++)
#pragma unroll
        for (int j = 0; j < 4; j++) acc[a].i[j] = 0;
    float s_l = 0.f;
    for (int b8 = 0; b8 < dg; b8 += 8) {          // octet-uniform trip count
        int rem = dg - b8;                        // octet-uniform
        int p = bk[start + b8 + ((r < rem) ? r : 0)];
#pragma unroll
        for (int j = 0; j < 8; j++) {
            if (j < rem) {                        // octet-uniform predicate
                int pj = __shfl(p, obase + j);    // source lane in same octet -> active
                HC wj; wj.us = (unsigned short)((unsigned)pj >> 16);
                s_l += (float)wj.h;
                HS row; row.u = *(const uint4*)(feat + (((pj & 0xFFFF) << 6) + roff));
                half_t wh = wj.h;
                half8 ws = {wh, wh, wh, wh, wh, wh, wh, wh};
                acc[j & 3].h += row.h * ws;
            }
        }
    }
    acc[0].h += acc[1].h;
    acc[2].h += acc[3].h;
    acc[0].h += acc[2].h;
    if (g < 4) {
        float inv = (dg > 0) ? __builtin_amdgcn_rcpf(s_l) : 0.f;
        H8 o;
#pragma unroll
        for (int i = 0; i < 8; i++) {
            float x = (float)acc[0].h[i] * inv;
            x = (x > 0.f) ? x : (__expf(x) - 1.f);
            o.h[i] = (half_t)x;
        }
        if (vok) *(uint4*)(ga.zout[g] + (v << 7) + roff) = o.u;
        return;                                   // block-uniform (g uniform per block)
    }
    // ---- g >= 4: GraphConv — stage normalized aggregate in LDS, then fused transform ----
    int gg = g - 4;
    {
        float niv = (dg > 0) ? __builtin_amdgcn_rsqf((float)dg) : 1.0f;
        H8 o;
#pragma unroll
        for (int i = 0; i < 8; i++) o.h[i] = (half_t)((float)acc[0].h[i] * niv);
        *(uint4*)(&AS[wv * 8 + q][roff]) = o.u;   // fp16 rounding identical to old AGG path
    }
    __syncthreads();
    int cl = lane & 15, quad = lane >> 4;
    int tl = wv >> 1;                             // tile 0/1 (16 nodes each)
    const half_t* ar = &AS[tl * 16 + cl][quad * 8];
    half8 A0 = *(const half8*)(ar);
    half8 A1 = *(const half8*)(ar + 32);
    const half_t* wbase = W16 + gg * 8 * 64 * 8;
    half_t* hout = gc.hout[gg];
#pragma unroll
    for (int u = 0; u < 2; u++) {
        int nt = (wv & 1) * 2 + u;
        float bb = b_gc[gg * 64 + nt * 16 + cl];
        f32x4 c = {bb, bb, bb, bb};
        half8 B0 = *(const half8*)(wbase + ((nt * 2 + 0) * 64 + lane) * 8);
        half8 B1 = *(const half8*)(wbase + ((nt * 2 + 1) * 64 + lane) * 8);
        c = __builtin_amdgcn_mfma_f32_16x16x32_f16(A0, B0, c, 0, 0, 0);
        c = __builtin_amdgcn_mfma_f32_16x16x32_f16(A1, B1, c, 0, 0, 0);
#pragma unroll
        for (int r_ = 0; r_ < 4; r_++) {
            int node = nb * 32 + tl * 16 + quad * 4 + r_;
            if (node < NN) {
                float x = c[r_];
                x = (x > 0.f) ? x : (__expf(x) - 1.f);
                hout[node * 128 + nt * 16 + cl] = (half_t)x;
            }
        }
    }
}

// ---------------- semantic attention via MFMA: wave wv owns hidden slice [wv*32, wv*32+32).
// BATCH-4 double-buffered LDS staging; counted vmcnt(2) + raw s_barrier. Per-lane
// accumulation, one 64-lane reduce at the end.
__global__ __launch_bounds__(256) void sem_att_kernel(SemArgs sa, float* __restrict__ wsum) {
    __shared__ half_t As[2][4][1024];   // 2 bufs x 4 tiles x 2KB
    __shared__ float s0[4], s1[4];
    int inst = blockIdx.x / SEMB;
    int blk  = blockIdx.x % SEMB;
    int t = threadIdx.x;
    int wv = t >> 6, lane = t & 63;
    int quad = lane >> 4, cl = lane & 15;
    const half_t* z = sa.z[inst];
    const float* W1 = sa.W1[inst];
    half8 Bf[2][2];
    float b1v[2], w2v[2];
#pragma unroll
    for (int u = 0; u < 2; u++) {
        int nt = wv * 2 + u;
        int n = nt * 16 + cl;
#pragma unroll
        for (int kh = 0; kh < 2; kh++) {
#pragma unroll
            for (int j = 0; j < 8; j++) {
                int k = kh * 32 + quad * 8 + j;
                Bf[u][kh][j] = (half_t)W1[k * HHID + n];
            }
        }
        b1v[u] = sa.b1[inst][nt * 16 + cl];
        w2v[u] = sa.w2[inst][nt * 16 + cl];
    }
    float local0 = 0.f, local1 = 0.f;
    int K = (6250 - blk + SEMB - 1) / SEMB;   // 12 or 13 tiles for this block
    int B = (K + 3) / 4;

#define SEM_STAGE(buf, bb) { \
    int k_ = 4 * (bb) + wv; \
    if (k_ < K) { \
        int tp_ = blk + k_ * SEMB; \
        int m_ = (tp_ >= 3125) ? 1 : 0; \
        int tm_ = tp_ - m_ * 3125; \
        int n_ = lane >> 3; \
        int j_ = (lane & 7) * 8; \
        const half_t* sA_ = z + (size_t)(tm_ * 16 + n_) * 128 + m_ * 64 + j_; \
        const half_t* sB_ = z + (size_t)(tm_ * 16 + 8 + n_) * 128 + m_ * 64 + j_; \
        __builtin_amdgcn_global_load_lds( \
            (const __attribute__((address_space(1))) unsigned int*)sA_, \
            (__attribute__((address_space(3))) unsigned int*)(&As[buf][wv][0]), 16, 0, 0); \
        __builtin_amdgcn_global_load_lds( \
            (const __attribute__((address_space(1))) unsigned int*)sB_, \
            (__attribute__((address_space(3))) unsigned int*)(&As[buf][wv][512]), 16, 0, 0); \
    } }

    int cur = 0;
    SEM_STAGE(0, 0);
    for (int b = 0; b < B; b++) {
        if (b + 1 < B) {
            SEM_STAGE(cur ^ 1, b + 1);
            asm volatile("s_waitcnt vmcnt(2)" ::: "memory");   // batch b done; b+1 in flight
        } else {
            asm volatile("s_waitcnt vmcnt(0)" ::: "memory");
        }
        __builtin_amdgcn_sched_barrier(0);
        __builtin_amdgcn_s_barrier();                          // raw: no vmcnt(0) drain
#pragma unroll
        for (int i = 0; i < 4; i++) {
            int k = 4 * b + i;
            if (k < K) {                                       // block-uniform
                int tile = blk + k * SEMB;
                const half_t* ar = &As[cur][i][cl * 64 + quad * 8];
                half8 A0 = *(const half8*)(ar);
                half8 A1 = *(const half8*)(ar + 32);
                float sumv = 0.f;
#pragma unroll
                for (int u = 0; u < 2; u++) {
                    f32x4 c = {0.f, 0.f, 0.f, 0.f};
                    c = __builtin_amdgcn_mfma_f32_16x16x32_f16(A0, Bf[u][0], c, 0, 0, 0);
                    c = __builtin_amdgcn_mfma_f32_16x16x32_f16(A1, Bf[u][1], c, 0, 0, 0);
#pragma unroll
                    for (int r = 0; r < 4; r++) {
                        float xv = c[r] + b1v[u];
                        float ev = __expf(2.f * xv);
                        float th = 1.f - 2.f * __builtin_amdgcn_rcpf(ev + 1.f);  // tanh
                        sumv += th * w2v[u];
                    }
                }
                if (tile < 3125) local0 += sumv; else local1 += sumv;
            }
        }
        __builtin_amdgcn_s_barrier();                          // readers done before re-stage
        cur ^= 1;
    }
#undef SEM_STAGE
#pragma unroll
    for (int off = 32; off > 0; off >>= 1) {
        local0 += __shfl_down(local0, off);
        local1 += __shfl_down(local1, off);
    }
    if (lane == 0) { s0[wv] = local0; s1[wv] = local1; }
    __syncthreads();
    if (t == 0) {
        float a0 = s0[0] + s0[1] + s0[2] + s0[3];
        float a1 = s1[0] + s1[1] + s1[2] + s1[3];
        if (a0 != 0.f) atomicAdd(&wsum[inst * 2 + 0], a0);
        if (a1 != 0.f) atomicAdd(&wsum[inst * 2 + 1], a1);
    }
}

// ---------------- final combine: thread = 4 consecutive output cols
__global__ void combine_kernel(const half_t* __restrict__ ZU, const half_t* __restrict__ ZI,
                               const half_t* __restrict__ HU, const half_t* __restrict__ HI,
                               const float* __restrict__ wsum, float* __restrict__ out) {
    int gid = blockIdx.x * blockDim.x + threadIdx.x;
    if (gid >= (NU + NI) * 16) return;
    int node = gid >> 4;
    int c4 = (gid & 15) * 4;
    const half_t* zb; const half_t* hb;
    float wr0, wr1, wh0, wh1;
    int idx;
    if (node < NU) {
        zb = ZU; hb = HU; idx = node;
        wr0 = wsum[0]; wr1 = wsum[1]; wh0 = wsum[4]; wh1 = wsum[5];
    } else {
        zb = ZI; hb = HI; idx = node - NU;
        wr0 = wsum[2]; wr1 = wsum[3]; wh0 = wsum[6]; wh1 = wsum[7];
    }
    const float inv_n = 1.0f / 50000.0f;
    wr0 *= inv_n; wr1 *= inv_n; wh0 *= inv_n; wh1 *= inv_n;
    float m = fmaxf(wr0, wr1);
    float e0 = __expf(wr0 - m), e1 = __expf(wr1 - m);
    float br0 = e0 / (e0 + e1), br1 = e1 / (e0 + e1);
    m = fmaxf(wh0, wh1);
    e0 = __expf(wh0 - m); e1 = __expf(wh1 - m);
    float bh0 = e0 / (e0 + e1), bh1 = e1 / (e0 + e1);
    H4 z0, z1, h0, h1;
    z0.u = *(const uint2*)(zb + idx * 128 + c4);
    z1.u = *(const uint2*)(zb + idx * 128 + 64 + c4);
    h0.u = *(const uint2*)(hb + idx * 128 + c4);
    h1.u = *(const uint2*)(hb + idx * 128 + 64 + c4);
    float4 o;
    o.x = (float)z0.h[0] * br0 + (float)z1.h[0] * br1 + (float)h0.h[0] * bh0 + (float)h1.h[0] * bh1;
    o.y = (float)z0.h[1] * br0 + (float)z1.h[1] * br1 + (float)h0.h[1] * bh0 + (float)h1.h[1] * bh1;
    o.z = (float)z0.h[2] * br0 + (float)z1.h[2] * br1 + (float)h0.h[2] * bh0 + (float)h1.h[2] * bh1;
    o.w = (float)z0.h[3] * br0 + (float)z1.h[3] * br1 + (float)h0.h[3] * bh0 + (float)h1.h[3] * bh1;
    *(float4*)(out + node * 64 + c4) = o;
}

extern "C" void kernel_launch(void* const* d_in, const int* in_sizes, int n_in,
                              void* d_out, int out_size, void* d_ws, size_t ws_size,
                              hipStream_t stream) {
    const float* feat_user = (const float*)d_in[0];
    const float* feat_item = (const float*)d_in[1];
    const float* attn_l    = (const float*)d_in[2];
    const float* attn_r    = (const float*)d_in[3];
    const float* W_gc      = (const float*)d_in[4];
    const float* b_gc      = (const float*)d_in[5];
    const float* sa_rel_W1 = (const float*)d_in[6];
    const float* sa_rel_b1 = (const float*)d_in[7];
    const float* sa_rel_w2 = (const float*)d_in[8];
    const float* sa_u_W1   = (const float*)d_in[9];
    const float* sa_u_b1   = (const float*)d_in[10];
    const float* sa_u_w2   = (const float*)d_in[11];
    const float* sa_i_W1   = (const float*)d_in[12];
    const float* sa_i_b1   = (const float*)d_in[13];
    const float* sa_i_w2   = (const float*)d_in[14];
    const int* rel_u_src = (const int*)d_in[15];
    const int* rel_u_dst = (const int*)d_in[16];
    const int* rel_i_src = (const int*)d_in[17];
    const int* rel_i_dst = (const int*)d_in[18];
    const int* mp_u_src  = (const int*)d_in[19];
    const int* mp_u_dst  = (const int*)d_in[20];
    const int* mp_i_src  = (const int*)d_in[21];
    const int* mp_i_dst  = (const int*)d_in[22];

    // ---- workspace layout ----
    half_t* ZU   = (half_t*)d_ws;             // NN*128 fp16
    half_t* ZI   = ZU + NN * 128;
    half_t* HU   = ZI + NN * 128;
    half_t* HI   = HU + NN * 128;
    half_t* FBU  = HI + NN * 128;             // fp16 feat_user, NN*64
    half_t* FBI  = FBU + NN * 64;             // fp16 feat_item, NN*64
    float*  DI   = (float*)(FBI + NN * 64);   // 4*NN
    float*  DU   = DI + 4 * NN;               // 4*NN
    int2*   RD   = (int2*)(DU + 4 * NN);      // 8*NN {row_start, deg}
    int*    BUCKET = (int*)(RD + 8 * NN);     // 8*EE (packed w16|src)
    int*    CCNT = BUCKET + 8 * EE;           // 12*256 -- zeroed
    int*    DEG_SRC = CCNT + 12 * 256;        // 4*NN   -- fully written by degcnt
    float*  WSUM = (float*)(DEG_SRC + 4 * NN);// 8      -- zeroed
    half_t* W16  = (half_t*)(WSUM + 8);       // 4*4096 fp16 fragment-ordered W
    int*    COARSE = (int*)d_ws;              // 12*196*CAP ints (28.9MB), aliases ZU..HI; dead before agg

    hipMemsetAsync(CCNT, 0, (size_t)(12 * 256 + 4 * NN) * sizeof(int) + 8 * sizeof(float), stream);

    // ---- merged CSR-partition + prep (independent halves, co-scheduled) ----
    PrepArgs pa;
    pa.featI = feat_item; pa.featU = feat_user;
    pa.vi = Ptr4c{{ attn_l + 0 * DD, attn_l + 1 * DD, attn_r + 2 * DD, attn_r + 3 * DD }};
    pa.oi = Ptr4m{{ DI, DI + NI, DI + 2 * NI, DI + 3 * NI }};
    pa.vu = Ptr4c{{ attn_l + 2 * DD, attn_l + 3 * DD, attn_r + 0 * DD, attn_r + 1 * DD }};
    pa.ou = Ptr4m{{ DU, DU + NU, DU + 2 * NU, DU + 3 * NU }};
    pa.FBI = FBI; pa.FBU = FBU;
    pa.W_gc = W_gc; pa.W16 = W16;

    EdgeArgs ea;
    ea.src[0] = rel_u_src;      ea.dst[0] = rel_u_dst;
    ea.src[1] = rel_u_src + EE; ea.dst[1] = rel_u_dst + EE;
    ea.src[2] = rel_i_src;      ea.dst[2] = rel_i_dst;
    ea.src[3] = rel_i_src + EE; ea.dst[3] = rel_i_dst + EE;
    ea.src[4] = mp_u_src;       ea.dst[4] = mp_u_dst;
    ea.src[5] = mp_u_src + EE;  ea.dst[5] = mp_u_dst + EE;
    ea.src[6] = mp_i_src;       ea.dst[6] = mp_i_dst;
    ea.src[7] = mp_i_src + EE;  ea.dst[7] = mp_i_dst + EE;

    build_kernel<<<P1B + 3126, P1T, 0, stream>>>(ea, CCNT, COARSE, pa);
    degcnt_kernel<<<4 * NBKT, 256, 0, stream>>>(CCNT, COARSE, DEG_SRC);

    WArgs wa;
    wa.el[0] = DI;      wa.er[0] = DU + 2 * NU;
    wa.el[1] = DI + NI; wa.er[1] = DU + 3 * NU;
    wa.el[2] = DU;      wa.er[2] = DI + 2 * NI;
    wa.el[3] = DU + NU; wa.er[3] = DI + 3 * NI;
    wa.deg_src = DEG_SRC;
    part2_kernel<<<8 * NBKT, 256, 0, stream>>>(CCNT, COARSE, wa, BUCKET, RD);

    // ---- fused aggregation + GC transform (8 graphs, octet-per-node) ----
    GatArgs ga;
    ga.fsrc[0] = FBI; ga.zout[0] = ZU;
    ga.fsrc[1] = FBI; ga.zout[1] = ZU + 64;
    ga.fsrc[2] = FBU; ga.zout[2] = ZI;
    ga.fsrc[3] = FBU; ga.zout[3] = ZI + 64;
    GcArgs gc;
    gc.feat[0] = FBU; gc.hout[0] = HU;
    gc.feat[1] = FBU; gc.hout[1] = HU + 64;
    gc.feat[2] = FBI; gc.hout[2] = HI;
    gc.feat[3] = FBI; gc.hout[3] = HI + 64;
    agg_kernel<<<8 * AGGB, 256, 0, stream>>>(ga, gc, W16, b_gc, RD, BUCKET);

    // ---- semantic attention (4 instances x SEMB blocks, batch-4 LDS pipeline) ----
    SemArgs sa;
    sa.z[0] = ZU; sa.W1[0] = sa_rel_W1; sa.b1[0] = sa_rel_b1; sa.w2[0] = sa_rel_w2;
    sa.z[1] = ZI; sa.W1[1] = sa_rel_W1; sa.b1[1] = sa_rel_b1; sa.w2[1] = sa_rel_w2;
    sa.z[2] = HU; sa.W1[2] = sa_u_W1;   sa.b1[2] = sa_u_b1;   sa.w2[2] = sa_u_w2;
    sa.z[3] = HI; sa.W1[3] = sa_i_W1;   sa.b1[3] = sa_i_b1;   sa.w2[3] = sa_i_w2;
    sem_att_kernel<<<4 * SEMB, 256, 0, stream>>>(sa, WSUM);

    // ---- combine ----
    combine_kernel<<<((NU + NI) * 16 + 255) / 256, 256, 0, stream>>>(ZU, ZI, HU, HI, WSUM, (float*)d_out);
}

// Round 15
// 312.577 us; speedup vs baseline: 1.2353x; 1.0256x over previous
//
#include <hip/hip_runtime.h>
#include <math.h>

#define NU 50000
#define NI 50000
#define NN 50000
#define DD 64
#define HHID 128
#define EE 500000
#define NEG_SLOPE 0.01f
#define NBKT 196           // coarse buckets of 256 nodes (key>>8)
#define CAP 3072           // capacity per (image,bucket) coarse region (mean 2551, +10 sigma)
#define TILE 8192          // tiles; tile_n always %4 == 0
#define TPG 62             // tiles per graph = ceil(500000/8192)
#define P1T 512            // build_kernel threads per block
#define NIMG 12            // 8 dst-keyed CSR images + 4 src-keyed count-only images
#define P1B (NIMG * TPG)   // 744 part1-style blocks (dispatched first)
#define AGGB 1563          // agg blocks per graph = ceil(50000/32)
#define SEMB 512           // sem_att blocks per instance

typedef _Float16 half_t;
typedef _Float16 half8 __attribute__((ext_vector_type(8)));
typedef float f32x4 __attribute__((ext_vector_type(4)));
union H4 { uint2 u; half_t h[4]; };
union H8 { uint4 u; half_t h[8]; };
union HS { half8 h; int i[4]; uint4 u; };
union HC { unsigned short us; half_t h; };

struct Ptr4c { const float* p[4]; };
struct Ptr4m { float*       p[4]; };
struct EdgeArgs { const int* src[8]; const int* dst[8]; };
struct GatArgs { const half_t* fsrc[4]; half_t* zout[4]; };
struct GcArgs  { const half_t* feat[4]; half_t* hout[4]; };
struct WArgs   { const float* el[4]; const float* er[4]; };
struct SemArgs { const half_t* z[4]; const float* W1[4]; const float* b1[4]; const float* w2[4]; };
struct PrepArgs {
    const float* featI; const float* featU;
    Ptr4c vi; Ptr4c vu; Ptr4m oi; Ptr4m ou;
    half_t* FBI; half_t* FBU;
    const float* W_gc; half_t* W16;
};

// ---------------- merged build: blocks [0,P1B) = part1 LDS counting-sort (12 keyed images),
// blocks [P1B, P1B+3126) = prep (fp16-cvt + dots; last block = W fragments).
__global__ __launch_bounds__(P1T) void build_kernel(EdgeArgs a, int* __restrict__ ccnt,
                                                    int* __restrict__ coarse, PrepArgs pa) {
    __shared__ int bc_cnt[256], bc_scan[256], bc_start[256], bc_cur[256], bc_gbase[256];
    __shared__ int stage[TILE];
    int t = threadIdx.x;
    if (blockIdx.x >= P1B) {
        // ---- prep half: 512 threads = 2 old 256-thread prep blocks ----
        int pb = blockIdx.x - P1B;
        if (pb == 3125) {
            if (t < 256) {
                int g = t >> 6;
                int lane = t & 63;
                int cl = lane & 15, quad = lane >> 4;
#pragma unroll
                for (int nt = 0; nt < 4; nt++) {
#pragma unroll
                    for (int kh = 0; kh < 2; kh++) {
                        H8 o;
#pragma unroll
                        for (int j = 0; j < 8; j++) {
                            int k = kh * 32 + quad * 8 + j;
                            int n = nt * 16 + cl;
                            o.h[j] = (half_t)pa.W_gc[g * 4096 + k * 64 + n];
                        }
                        *(uint4*)(pa.W16 + ((g * 8 + nt * 2 + kh) * 64 + lane) * 8) = o.u;
                    }
                }
            }
            return;
        }
        int ob = pb * 2 + (t >> 8);      // old prep block id in [0, 6250)
        int t256 = t & 255;
        const float* feat; Ptr4c vecs; Ptr4m outs; half_t* fb16; int bb;
        if (ob < 3125) { feat = pa.featI; vecs = pa.vi; outs = pa.oi; fb16 = pa.FBI; bb = ob; }
        else           { feat = pa.featU; vecs = pa.vu; outs = pa.ou; fb16 = pa.FBU; bb = ob - 3125; }
        int w = bb * 4 + (t256 >> 6);
        int lane = t256 & 63;
        int sub = lane >> 4, r = lane & 15;
        int node = w * 4 + sub;          // <= 49999 by construction
        float4 f = *(const float4*)(feat + node * DD + r * 4);
        H4 o16;
        o16.h[0] = (half_t)f.x; o16.h[1] = (half_t)f.y; o16.h[2] = (half_t)f.z; o16.h[3] = (half_t)f.w;
        *(uint2*)(fb16 + node * DD + r * 4) = o16.u;
#pragma unroll
        for (int j = 0; j < 4; j++) {
            float4 vv = *(const float4*)(vecs.p[j] + r * 4);
            float val = f.x * vv.x + f.y * vv.y + f.z * vv.z + f.w * vv.w;
            val += __shfl_down(val, 8);
            val += __shfl_down(val, 4);
            val += __shfl_down(val, 2);
            val += __shfl_down(val, 1);
            if (r == 0) outs.p[j][node] = val;
        }
        return;
    }
    // ---- part1 half: two-phase LDS counting-sort; NO global atomics ----
    int g = blockIdx.x / TPG;
    int tile = blockIdx.x % TPG;
    int e0 = tile * TILE;
    int tile_n = min(TILE, EE - e0);      // always % 4 == 0
    bool cnt_only = g >= 8;
    const int* gk = (cnt_only ? a.src[g - 4] : a.dst[g]) + e0;
    const int* gs = cnt_only ? gk : (a.src[g] + e0);
    if (t < 256) bc_cnt[t] = 0;
    __syncthreads();
    // phase A: key histogram (streaming int4)
    for (int pos = t * 4; pos < tile_n; pos += P1T * 4) {
        int4 k4 = *(const int4*)(gk + pos);
        atomicAdd(&bc_cnt[k4.x >> 8], 1);
        atomicAdd(&bc_cnt[k4.y >> 8], 1);
        atomicAdd(&bc_cnt[k4.z >> 8], 1);
        atomicAdd(&bc_cnt[k4.w >> 8], 1);
    }
    __syncthreads();
    if (t < 256) bc_scan[t] = bc_cnt[t];
    __syncthreads();
    for (int off = 1; off < 256; off <<= 1) {
        int v = (t < 256 && t >= off) ? bc_scan[t - off] : 0;
        __syncthreads();
        if (t < 256) bc_scan[t] += v;
        __syncthreads();
    }
    if (t < 256) {
        int st = bc_scan[t] - bc_cnt[t];
        bc_start[t] = st;
        bc_cur[t] = st;
        bc_gbase[t] = (t < NBKT && bc_cnt[t] > 0) ? atomicAdd(&ccnt[g * NBKT + t], bc_cnt[t]) : 0;
    }
    __syncthreads();
    // phase B: re-read keys (L2-hot), LDS scatter with packed bucket id
    for (int pos = t * 4; pos < tile_n; pos += P1T * 4) {
        int4 k4 = *(const int4*)(gk + pos);
        int4 s4;
        if (cnt_only) { s4 = make_int4(0, 0, 0, 0); }
        else          { s4 = *(const int4*)(gs + pos); }
        int b0 = k4.x >> 8, b1 = k4.y >> 8, b2 = k4.z >> 8, b3 = k4.w >> 8;
        int sl0 = atomicAdd(&bc_cur[b0], 1);
        int sl1 = atomicAdd(&bc_cur[b1], 1);
        int sl2 = atomicAdd(&bc_cur[b2], 1);
        int sl3 = atomicAdd(&bc_cur[b3], 1);
        stage[sl0] = s4.x | ((k4.x & 255) << 16) | (b0 << 24);
        stage[sl1] = s4.y | ((k4.y & 255) << 16) | (b1 << 24);
        stage[sl2] = s4.z | ((k4.z & 255) << 16) | (b2 << 24);
        stage[sl3] = s4.w | ((k4.w & 255) << 16) | (b3 << 24);
    }
    __syncthreads();
    // flush: bucket-sorted stage -> long contiguous global runs
    for (int j = t; j < tile_n; j += P1T) {
        int p = stage[j];
        int b = (unsigned)p >> 24;
        int pos = bc_gbase[b] + (j - bc_start[b]);
        if (pos < CAP) coarse[(g * NBKT + b) * CAP + pos] = p & 0x00FFFFFF;
    }
}

// ---------------- pass 2 (merged with degcnt): grid = 12*NBKT.
// g in [0,8): per (graph,bucket) counting sort -> CSR with packed entries.
//   g<4: entry = (w16<<16 | src), w = exp(leaky(el+er)) computed here.
//   g>=4: entry = src only -- the GC weight rsqrt(deg_src) is computed in agg now,
//         which removes this launch's dependency on DEG_SRC and lets the degcnt
//         blocks (g in [8,12)) run in the SAME launch (saves the degcnt dispatch).
__global__ __launch_bounds__(256) void part2_kernel(const int* __restrict__ ccnt,
                                                    const int* __restrict__ coarse,
                                                    WArgs wa,
                                                    int* __restrict__ bucket,
                                                    int2* __restrict__ RD,
                                                    int* __restrict__ DEG_SRC) {
    __shared__ int sb[256];
    __shared__ int cnt5[256], off5[256], s2[256];
    __shared__ int ordered[CAP];
    int t = threadIdx.x;
    int g = blockIdx.x / NBKT;
    int b = blockIdx.x % NBKT;
    if (g >= 8) {
        // ---- degcnt body: LDS histogram of 256 local src ids, coalesced DEG_SRC write ----
        int n = min(ccnt[g * NBKT + b], CAP);
        cnt5[t] = 0;
        __syncthreads();
        const int* pairs = coarse + (g * NBKT + b) * CAP;
        for (int i = t; i < n; i += 256) atomicAdd(&cnt5[(pairs[i] >> 16) & 255], 1);
        __syncthreads();
        int v = (b << 8) + t;
        if (v < NN) DEG_SRC[(g - 8) * NN + v] = cnt5[t];
        return;
    }
    int ccv = (t < NBKT) ? min(ccnt[g * NBKT + t], CAP) : 0;
    sb[t] = ccv;
    cnt5[t] = 0;
    __syncthreads();
    for (int off = 1; off < 256; off <<= 1) {
        int vv = (t >= off) ? sb[t - off] : 0;
        __syncthreads();
        sb[t] += vv;
        __syncthreads();
    }
    int base = (b > 0) ? sb[b - 1] : 0;
    int n = sb[b] - base;
    int node0 = b << 8;
    const int* pairs = coarse + (g * NBKT + b) * CAP;
    for (int i = t; i < n; i += 256) atomicAdd(&cnt5[pairs[i] >> 16], 1);
    __syncthreads();
    int myc = cnt5[t];
    s2[t] = myc;
    __syncthreads();
    for (int off = 1; off < 256; off <<= 1) {
        int vv = (t >= off) ? s2[t - off] : 0;
        __syncthreads();
        s2[t] += vv;
        __syncthreads();
    }
    int ex = s2[t] - myc;
    off5[t] = ex;
    int v = node0 + t;
    if (v < NN) RD[g * NN + v] = make_int2(base + ex, myc);
    __syncthreads();
    int nm1 = n - 1;
    for (int ib = t; ib < n; ib += 1024) {
        int p[4];
#pragma unroll
        for (int u = 0; u < 4; u++) {
            int i = ib + u * 256;
            p[u] = pairs[(i < n) ? i : nm1];
        }
        float w[4];
        if (g < 4) {
            float a0[4], a1[4];
#pragma unroll
            for (int u = 0; u < 4; u++) a0[u] = wa.el[g][p[u] & 0xFFFF];
#pragma unroll
            for (int u = 0; u < 4; u++) a1[u] = wa.er[g][node0 + (p[u] >> 16)];
#pragma unroll
            for (int u = 0; u < 4; u++) {
                float e = a0[u] + a1[u];
                e = (e >= 0.f) ? e : NEG_SLOPE * e;
                w[u] = __expf(e);
            }
        }
#pragma unroll
        for (int u = 0; u < 4; u++) {
            int i = ib + u * 256;
            if (i < n) {
                int ent;
                if (g < 4) { HC cv; cv.h = (half_t)w[u]; ent = (p[u] & 0xFFFF) | ((int)cv.us << 16); }
                else       { ent = p[u] & 0xFFFF; }
                int slot = atomicAdd(&off5[p[u] >> 16], 1);
                ordered[slot] = ent;
            }
        }
    }
    __syncthreads();
    int* bko = bucket + g * EE + base;
    for (int i = t; i < n; i += 256) bko[i] = ordered[i];
}

// ---------------- fused aggregation + GC transform, octet-per-node.
// Gather loop near-floor (66-71us, 3.16TB/s L2-miss path). g>=4: the GC edge weight
// rsqrt(deg_src) is computed HERE (same int input + same rsqf + fp16 cast as the old
// part2 path -> bit-identical), re-packed into p's high bits so the j-loop is unchanged.
// AS padded to 72 halfs/row: read stride 144B spreads cl-lanes across 8 bank windows.
__global__ __launch_bounds__(256) void agg_kernel(GatArgs ga, GcArgs gc,
                                                  const half_t* __restrict__ W16,
                                                  const float* __restrict__ b_gc,
                                                  const int2* __restrict__ RD,
                                                  const int* __restrict__ bucket,
                                                  const int* __restrict__ DEG_SRC) {
    __shared__ half_t AS[32][72];     // padded: 144B rows -> 8 bank windows on fragment reads
    int g = blockIdx.x / AGGB;
    int nb = blockIdx.x % AGGB;
    int t = threadIdx.x;
    int wv = t >> 6, lane = t & 63;
    int q = lane >> 3, r = lane & 7;
    int v = nb * 32 + wv * 8 + q;
    bool vok = v < NN;
    int2 rd = RD[g * NN + (vok ? v : 0)];
    int start = rd.x;
    int dg = vok ? rd.y : 0;
    const int* bk = bucket + g * EE;
    const half_t* feat = (g < 4) ? ga.fsrc[g] : gc.feat[g - 4];
    const int* degtab = DEG_SRC + (g >= 4 ? (g - 4) * NN : 0);
    int roff = r << 3;
    int obase = lane & 56;            // q*8 = base lane of this octet
    HS acc[4];
#pragma unroll
    for (int a = 0; a < 4; a++)
#pragma unroll
        for (int j = 0; j < 4; j++) acc[a].i[j] = 0;
    float s_l = 0.f;
    for (int b8 = 0; b8 < dg; b8 += 8) {          // octet-uniform trip count
        int rem = dg - b8;                        // octet-uniform
        int p = bk[start + b8 + ((r < rem) ? r : 0)];
        if (g >= 4) {                             // block-uniform: compute + pack GC weight
            int dsv = degtab[p & 0xFFFF];         // dup lanes gather valid idx, never consumed
            HC cv; cv.h = (half_t)__builtin_amdgcn_rsqf((float)dsv);
            p = (p & 0xFFFF) | ((int)cv.us << 16);
        }
#pragma unroll
        for (int j = 0; j < 8; j++) {
            if (j < rem) {                        // octet-uniform predicate
                int pj = __shfl(p, obase + j);    // source lane in same octet -> active
                HC wj; wj.us = (unsigned short)((unsigned)pj >> 16);
                s_l += (float)wj.h;
                HS row; row.u = *(const uint4*)(feat + (((pj & 0xFFFF) << 6) + roff));
                half_t wh = wj.h;
                half8 ws = {wh, wh, wh, wh, wh, wh, wh, wh};
                acc[j & 3].h += row.h * ws;
            }
        }
    }
    acc[0].h += acc[1].h;
    acc[2].h += acc[3].h;
    acc[0].h += acc[2].h;
    if (g < 4) {
        float inv = (dg > 0) ? __builtin_amdgcn_rcpf(s_l) : 0.f;
        H8 o;
#pragma unroll
        for (int i = 0; i < 8; i++) {
            float x = (float)acc[0].h[i] * inv;
            x = (x > 0.f) ? x : (__expf(x) - 1.f);
            o.h[i] = (half_t)x;
        }
        if (vok) *(uint4*)(ga.zout[g] + (v << 7) + roff) = o.u;
        return;                                   // block-uniform (g uniform per block)
    }
    // ---- g >= 4: GraphConv — stage normalized aggregate in LDS, then fused transform ----
    int gg = g - 4;
    {
        float niv = (dg > 0) ? __builtin_amdgcn_rsqf((float)dg) : 1.0f;
        H8 o;
#pragma unroll
        for (int i = 0; i < 8; i++) o.h[i] = (half_t)((float)acc[0].h[i] * niv);
        *(uint4*)(&AS[wv * 8 + q][roff]) = o.u;   // fp16 rounding identical to old AGG path
    }
    __syncthreads();
    int cl = lane & 15, quad = lane >> 4;
    int tl = wv >> 1;                             // tile 0/1 (16 nodes each)
    const half_t* ar = &AS[tl * 16 + cl][quad * 8];
    half8 A0 = *(const half8*)(ar);
    half8 A1 = *(const half8*)(ar + 32);
    const half_t* wbase = W16 + gg * 8 * 64 * 8;
    half_t* hout = gc.hout[gg];
#pragma unroll
    for (int u = 0; u < 2; u++) {
        int nt = (wv & 1) * 2 + u;
        float bb = b_gc[gg * 64 + nt * 16 + cl];
        f32x4 c = {bb, bb, bb, bb};
        half8 B0 = *(const half8*)(wbase + ((nt * 2 + 0) * 64 + lane) * 8);
        half8 B1 = *(const half8*)(wbase + ((nt * 2 + 1) * 64 + lane) * 8);
        c = __builtin_amdgcn_mfma_f32_16x16x32_f16(A0, B0, c, 0, 0, 0);
        c = __builtin_amdgcn_mfma_f32_16x16x32_f16(A1, B1, c, 0, 0, 0);
#pragma unroll
        for (int r_ = 0; r_ < 4; r_++) {
            int node = nb * 32 + tl * 16 + quad * 4 + r_;
            if (node < NN) {
                float x = c[r_];
                x = (x > 0.f) ? x : (__expf(x) - 1.f);
                hout[node * 128 + nt * 16 + cl] = (half_t)x;
            }
        }
    }
}

// ---------------- semantic attention via MFMA: wave wv owns hidden slice [wv*32, wv*32+32).
// BATCH-4 double-buffered LDS staging; counted vmcnt(2) + raw s_barrier. Per-lane
// accumulation, one 64-lane reduce at the end.
__global__ __launch_bounds__(256) void sem_att_kernel(SemArgs sa, float* __restrict__ wsum) {
    __shared__ half_t As[2][4][1024];   // 2 bufs x 4 tiles x 2KB
    __shared__ float s0[4], s1[4];
    int inst = blockIdx.x / SEMB;
    int blk  = blockIdx.x % SEMB;
    int t = threadIdx.x;
    int wv = t >> 6, lane = t & 63;
    int quad = lane >> 4, cl = lane & 15;
    const half_t* z = sa.z[inst];
    const float* W1 = sa.W1[inst];
    half8 Bf[2][2];
    float b1v[2], w2v[2];
#pragma unroll
    for (int u = 0; u < 2; u++) {
        int nt = wv * 2 + u;
        int n = nt * 16 + cl;
#pragma unroll
        for (int kh = 0; kh < 2; kh++) {
#pragma unroll
            for (int j = 0; j < 8; j++) {
                int k = kh * 32 + quad * 8 + j;
                Bf[u][kh][j] = (half_t)W1[k * HHID + n];
            }
        }
        b1v[u] = sa.b1[inst][nt * 16 + cl];
        w2v[u] = sa.w2[inst][nt * 16 + cl];
    }
    float local0 = 0.f, local1 = 0.f;
    int K = (6250 - blk + SEMB - 1) / SEMB;   // 12 or 13 tiles for this block
    int B = (K + 3) / 4;

#define SEM_STAGE(buf, bb) { \
    int k_ = 4 * (bb) + wv; \
    if (k_ < K) { \
        int tp_ = blk + k_ * SEMB; \
        int m_ = (tp_ >= 3125) ? 1 : 0; \
        int tm_ = tp_ - m_ * 3125; \
        int n_ = lane >> 3; \
        int j_ = (lane & 7) * 8; \
        const half_t* sA_ = z + (size_t)(tm_ * 16 + n_) * 128 + m_ * 64 + j_; \
        const half_t* sB_ = z + (size_t)(tm_ * 16 + 8 + n_) * 128 + m_ * 64 + j_; \
        __builtin_amdgcn_global_load_lds( \
            (const __attribute__((address_space(1))) unsigned int*)sA_, \
            (__attribute__((address_space(3))) unsigned int*)(&As[buf][wv][0]), 16, 0, 0); \
        __builtin_amdgcn_global_load_lds( \
            (const __attribute__((address_space(1))) unsigned int*)sB_, \
            (__attribute__((address_space(3))) unsigned int*)(&As[buf][wv][512]), 16, 0, 0); \
    } }

    int cur = 0;
    SEM_STAGE(0, 0);
    for (int b = 0; b < B; b++) {
        if (b + 1 < B) {
            SEM_STAGE(cur ^ 1, b + 1);
            asm volatile("s_waitcnt vmcnt(2)" ::: "memory");   // batch b done; b+1 in flight
        } else {
            asm volatile("s_waitcnt vmcnt(0)" ::: "memory");
        }
        __builtin_amdgcn_sched_barrier(0);
        __builtin_amdgcn_s_barrier();                          // raw: no vmcnt(0) drain
#pragma unroll
        for (int i = 0; i < 4; i++) {
            int k = 4 * b + i;
            if (k < K) {                                       // block-uniform
                int tile = blk + k * SEMB;
                const half_t* ar = &As[cur][i][cl * 64 + quad * 8];
                half8 A0 = *(const half8*)(ar);
                half8 A1 = *(const half8*)(ar + 32);
                float sumv = 0.f;
#pragma unroll
                for (int u = 0; u < 2; u++) {
                    f32x4 c = {0.f, 0.f, 0.f, 0.f};
                    c = __builtin_amdgcn_mfma_f32_16x16x32_f16(A0, Bf[u][0], c, 0, 0, 0);
                    c = __builtin_amdgcn_mfma_f32_16x16x32_f16(A1, Bf[u][1], c, 0, 0, 0);
#pragma unroll
                    for (int r = 0; r < 4; r++) {
                        float xv = c[r] + b1v[u];
                        float ev = __expf(2.f * xv);
                        float th = 1.f - 2.f * __builtin_amdgcn_rcpf(ev + 1.f);  // tanh
                        sumv += th * w2v[u];
                    }
                }
                if (tile < 3125) local0 += sumv; else local1 += sumv;
            }
        }
        __builtin_amdgcn_s_barrier();                          // readers done before re-stage
        cur ^= 1;
    }
#undef SEM_STAGE
#pragma unroll
    for (int off = 32; off > 0; off >>= 1) {
        local0 += __shfl_down(local0, off);
        local1 += __shfl_down(local1, off);
    }
    if (lane == 0) { s0[wv] = local0; s1[wv] = local1; }
    __syncthreads();
    if (t == 0) {
        float a0 = s0[0] + s0[1] + s0[2] + s0[3];
        float a1 = s1[0] + s1[1] + s1[2] + s1[3];
        if (a0 != 0.f) atomicAdd(&wsum[inst * 2 + 0], a0);
        if (a1 != 0.f) atomicAdd(&wsum[inst * 2 + 1], a1);
    }
}

// ---------------- final combine: thread = 4 consecutive output cols
__global__ void combine_kernel(const half_t* __restrict__ ZU, const half_t* __restrict__ ZI,
                               const half_t* __restrict__ HU, const half_t* __restrict__ HI,
                               const float* __restrict__ wsum, float* __restrict__ out) {
    int gid = blockIdx.x * blockDim.x + threadIdx.x;
    if (gid >= (NU + NI) * 16) return;
    int node = gid >> 4;
    int c4 = (gid & 15) * 4;
    const half_t* zb; const half_t* hb;
    float wr0, wr1, wh0, wh1;
    int idx;
    if (node < NU) {
        zb = ZU; hb = HU; idx = node;
        wr0 = wsum[0]; wr1 = wsum[1]; wh0 = wsum[4]; wh1 = wsum[5];
    } else {
        zb = ZI; hb = HI; idx = node - NU;
        wr0 = wsum[2]; wr1 = wsum[3]; wh0 = wsum[6]; wh1 = wsum[7];
    }
    const float inv_n = 1.0f / 50000.0f;
    wr0 *= inv_n; wr1 *= inv_n; wh0 *= inv_n; wh1 *= inv_n;
    float m = fmaxf(wr0, wr1);
    float e0 = __expf(wr0 - m), e1 = __expf(wr1 - m);
    float br0 = e0 / (e0 + e1), br1 = e1 / (e0 + e1);
    m = fmaxf(wh0, wh1);
    e0 = __expf(wh0 - m); e1 = __expf(wh1 - m);
    float bh0 = e0 / (e0 + e1), bh1 = e1 / (e0 + e1);
    H4 z0, z1, h0, h1;
    z0.u = *(const uint2*)(zb + idx * 128 + c4);
    z1.u = *(const uint2*)(zb + idx * 128 + 64 + c4);
    h0.u = *(const uint2*)(hb + idx * 128 + c4);
    h1.u = *(const uint2*)(hb + idx * 128 + 64 + c4);
    float4 o;
    o.x = (float)z0.h[0] * br0 + (float)z1.h[0] * br1 + (float)h0.h[0] * bh0 + (float)h1.h[0] * bh1;
    o.y = (float)z0.h[1] * br0 + (float)z1.h[1] * br1 + (float)h0.h[1] * bh0 + (float)h1.h[1] * bh1;
    o.z = (float)z0.h[2] * br0 + (float)z1.h[2] * br1 + (float)h0.h[2] * bh0 + (float)h1.h[2] * bh1;
    o.w = (float)z0.h[3] * br0 + (float)z1.h[3] * br1 + (float)h0.h[3] * bh0 + (float)h1.h[3] * bh1;
    *(float4*)(out + node * 64 + c4) = o;
}

extern "C" void kernel_launch(void* const* d_in, const int* in_sizes, int n_in,
                              void* d_out, int out_size, void* d_ws, size_t ws_size,
                              hipStream_t stream) {
    const float* feat_user = (const float*)d_in[0];
    const float* feat_item = (const float*)d_in[1];
    const float* attn_l    = (const float*)d_in[2];
    const float* attn_r    = (const float*)d_in[3];
    const float* W_gc      = (const float*)d_in[4];
    const float* b_gc      = (const float*)d_in[5];
    const float* sa_rel_W1 = (const float*)d_in[6];
    const float* sa_rel_b1 = (const float*)d_in[7];
    const float* sa_rel_w2 = (const float*)d_in[8];
    const float* sa_u_W1   = (const float*)d_in[9];
    const float* sa_u_b1   = (const float*)d_in[10];
    const float* sa_u_w2   = (const float*)d_in[11];
    const float* sa_i_W1   = (const float*)d_in[12];
    const float* sa_i_b1   = (const float*)d_in[13];
    const float* sa_i_w2   = (const float*)d_in[14];
    const int* rel_u_src = (const int*)d_in[15];
    const int* rel_u_dst = (const int*)d_in[16];
    const int* rel_i_src = (const int*)d_in[17];
    const int* rel_i_dst = (const int*)d_in[18];
    const int* mp_u_src  = (const int*)d_in[19];
    const int* mp_u_dst  = (const int*)d_in[20];
    const int* mp_i_src  = (const int*)d_in[21];
    const int* mp_i_dst  = (const int*)d_in[22];

    // ---- workspace layout ----
    half_t* ZU   = (half_t*)d_ws;             // NN*128 fp16
    half_t* ZI   = ZU + NN * 128;
    half_t* HU   = ZI + NN * 128;
    half_t* HI   = HU + NN * 128;
    half_t* FBU  = HI + NN * 128;             // fp16 feat_user, NN*64
    half_t* FBI  = FBU + NN * 64;             // fp16 feat_item, NN*64
    float*  DI   = (float*)(FBI + NN * 64);   // 4*NN
    float*  DU   = DI + 4 * NN;               // 4*NN
    int2*   RD   = (int2*)(DU + 4 * NN);      // 8*NN {row_start, deg}
    int*    BUCKET = (int*)(RD + 8 * NN);     // 8*EE (packed entries)
    int*    CCNT = BUCKET + 8 * EE;           // 12*256 -- zeroed
    int*    DEG_SRC = CCNT + 12 * 256;        // 4*NN   -- fully written by part2's degcnt blocks
    float*  WSUM = (float*)(DEG_SRC + 4 * NN);// 8      -- zeroed
    half_t* W16  = (half_t*)(WSUM + 8);       // 4*4096 fp16 fragment-ordered W
    int*    COARSE = (int*)d_ws;              // 12*196*CAP ints (28.9MB), aliases ZU..HI; dead before agg

    hipMemsetAsync(CCNT, 0, (size_t)(12 * 256 + 4 * NN) * sizeof(int) + 8 * sizeof(float), stream);

    // ---- merged CSR-partition + prep (independent halves, co-scheduled) ----
    PrepArgs pa;
    pa.featI = feat_item; pa.featU = feat_user;
    pa.vi = Ptr4c{{ attn_l + 0 * DD, attn_l + 1 * DD, attn_r + 2 * DD, attn_r + 3 * DD }};
    pa.oi = Ptr4m{{ DI, DI + NI, DI + 2 * NI, DI + 3 * NI }};
    pa.vu = Ptr4c{{ attn_l + 2 * DD, attn_l + 3 * DD, attn_r + 0 * DD, attn_r + 1 * DD }};
    pa.ou = Ptr4m{{ DU, DU + NU, DU + 2 * NU, DU + 3 * NU }};
    pa.FBI = FBI; pa.FBU = FBU;
    pa.W_gc = W_gc; pa.W16 = W16;

    EdgeArgs ea;
    ea.src[0] = rel_u_src;      ea.dst[0] = rel_u_dst;
    ea.src[1] = rel_u_src + EE; ea.dst[1] = rel_u_dst + EE;
    ea.src[2] = rel_i_src;      ea.dst[2] = rel_i_dst;
    ea.src[3] = rel_i_src + EE; ea.dst[3] = rel_i_dst + EE;
    ea.src[4] = mp_u_src;       ea.dst[4] = mp_u_dst;
    ea.src[5] = mp_u_src + EE;  ea.dst[5] = mp_u_dst + EE;
    ea.src[6] = mp_i_src;       ea.dst[6] = mp_i_dst;
    ea.src[7] = mp_i_src + EE;  ea.dst[7] = mp_i_dst + EE;

    build_kernel<<<P1B + 3126, P1T, 0, stream>>>(ea, CCNT, COARSE, pa);

    WArgs wa;
    wa.el[0] = DI;      wa.er[0] = DU + 2 * NU;
    wa.el[1] = DI + NI; wa.er[1] = DU + 3 * NU;
    wa.el[2] = DU;      wa.er[2] = DI + 2 * NI;
    wa.el[3] = DU + NU; wa.er[3] = DI + 3 * NI;
    part2_kernel<<<12 * NBKT, 256, 0, stream>>>(CCNT, COARSE, wa, BUCKET, RD, DEG_SRC);

    // ---- fused aggregation + GC transform (8 graphs, octet-per-node) ----
    GatArgs ga;
    ga.fsrc[0] = FBI; ga.zout[0] = ZU;
    ga.fsrc[1] = FBI; ga.zout[1] = ZU + 64;
    ga.fsrc[2] = FBU; ga.zout[2] = ZI;
    ga.fsrc[3] = FBU; ga.zout[3] = ZI + 64;
    GcArgs gc;
    gc.feat[0] = FBU; gc.hout[0] = HU;
    gc.feat[1] = FBU; gc.hout[1] = HU + 64;
    gc.feat[2] = FBI; gc.hout[2] = HI;
    gc.feat[3] = FBI; gc.hout[3] = HI + 64;
    agg_kernel<<<8 * AGGB, 256, 0, stream>>>(ga, gc, W16, b_gc, RD, BUCKET, DEG_SRC);

    // ---- semantic attention (4 instances x SEMB blocks, batch-4 LDS pipeline) ----
    SemArgs sa;
    sa.z[0] = ZU; sa.W1[0] = sa_rel_W1; sa.b1[0] = sa_rel_b1; sa.w2[0] = sa_rel_w2;
    sa.z[1] = ZI; sa.W1[1] = sa_rel_W1; sa.b1[1] = sa_rel_b1; sa.w2[1] = sa_rel_w2;
    sa.z[2] = HU; sa.W1[2] = sa_u_W1;   sa.b1[2] = sa_u_b1;   sa.w2[2] = sa_u_w2;
    sa.z[3] = HI; sa.W1[3] = sa_i_W1;   sa.b1[3] = sa_i_b1;   sa.w2[3] = sa_i_w2;
    sem_att_kernel<<<4 * SEMB, 256, 0, stream>>>(sa, WSUM);

    // ---- combine ----
    combine_kernel<<<((NU + NI) * 16 + 255) / 256, 256, 0, stream>>>(ZU, ZI, HU, HI, WSUM, (float*)d_out);
}